// Round 14
// baseline (355.442 us; speedup 1.0000x reference)
//
#include <hip/hip_runtime.h>
#include <hip/hip_bf16.h>

// MoD transformer block: B=4, T=4096, D=1024, H=16, HD=64, CAP=512, DFF=2730
// Inputs fp32, output fp32. Round 14:
//  (a) GEMM staging via __builtin_amdgcn_global_load_lds (16B) into LINEAR LDS
//      with rule-#21 XOR swizzle (inverse-swizzled global source per lane +
//      swizzled ds_read). r13 GEMMs: MfmaUtil 7%, latency-bound reg-roundtrip.
//  (b) k_topk 1024 -> 256 threads (78 bitonic passes were 16-wave-barrier bound).

#define B_   4
#define T_   4096
#define D_   1024
#define H_   16
#define HD_  64
#define CAP_ 512
#define DFF_ 2730
#define DFFP 2752               // DFF padded to mult of 64 (K-path)
#define DFFR 2816               // DFF padded to mult of 128 (B-row tiles)
#define M_   (B_*CAP_)          // 2048 selected rows total

typedef __attribute__((ext_vector_type(8))) short          s16x8;
typedef __attribute__((ext_vector_type(8))) unsigned short u16x8;
typedef __attribute__((ext_vector_type(4))) float          f32x4;

__device__ __forceinline__ float bf2f(unsigned short u) {
    union { float f; unsigned int i; } v; v.i = ((unsigned int)u) << 16; return v.f;
}
__device__ __forceinline__ unsigned short f2bf(float f) {
    union { float f; unsigned int i; } v; v.f = f;
    unsigned int r = v.i + 0x7fffu + ((v.i >> 16) & 1u);   // RNE
    return (unsigned short)(r >> 16);
}

// async global->LDS, 16B per lane; LDS dest = wave-uniform base + lane*16
__device__ __forceinline__ void gload_lds16(const unsigned short* g, unsigned short* l) {
    __builtin_amdgcn_global_load_lds(
        (const __attribute__((address_space(1))) unsigned int*)g,
        (__attribute__((address_space(3))) unsigned int*)l, 16, 0, 0);
}

// ---------------- out = x pass-through (fp32 copy) ----------------
__global__ __launch_bounds__(256) void k_copyf(const float4* __restrict__ s,
                                               float4* __restrict__ d, int n4) {
    int i = blockIdx.x * 256 + threadIdx.x;
    int st = gridDim.x * 256;
    for (; i < n4; i += st) d[i] = s[i];
}

// ---------------- fp32 -> bf16 flat convert ----------------
__global__ __launch_bounds__(256) void k_f2b(const float4* __restrict__ s,
                                             ushort4* __restrict__ d, int n4) {
    int i = blockIdx.x * 256 + threadIdx.x;
    int st = gridDim.x * 256;
    for (; i < n4; i += st) {
        float4 v = s[i];
        ushort4 o;
        o.x = f2bf(v.x); o.y = f2bf(v.y); o.z = f2bf(v.z); o.w = f2bf(v.w);
        d[i] = o;
    }
}

// ---------------- fp32 [rows][K] -> bf16 [rowsP][K], pad ROWS zeroed ----------------
// kc = K/8; total = rowsP*kc
__global__ __launch_bounds__(256) void k_f2b_rowpad(const float* __restrict__ src,
                                                    unsigned short* __restrict__ dst,
                                                    int kc, int rows, int total) {
    int g = blockIdx.x * 256 + threadIdx.x;
    int st = gridDim.x * 256;
    for (; g < total; g += st) {
        int row = g / kc;
        u16x8 v = {0, 0, 0, 0, 0, 0, 0, 0};
        if (row < rows) {
            const float* s = src + ((size_t)g) * 8;
#pragma unroll
            for (int j = 0; j < 2; ++j) {
                float4 f = *(const float4*)(s + 4 * j);
                v[4*j]   = f2bf(f.x); v[4*j+1] = f2bf(f.y);
                v[4*j+2] = f2bf(f.z); v[4*j+3] = f2bf(f.w);
            }
        }
        *(u16x8*)(dst + (size_t)g * 8) = v;
    }
}

// ---------------- fp32 [rows][K] -> bf16 [rows][Kp], pad COLS zeroed ----------------
__global__ __launch_bounds__(256) void k_f2b_pad(const float* __restrict__ src,
                                                 unsigned short* __restrict__ dst,
                                                 int K, int Kp, int rows) {
    int g = blockIdx.x * 256 + threadIdx.x;
    int ng = rows * (Kp >> 3);
    int st = gridDim.x * 256;
    for (; g < ng; g += st) {
        int row = g / (Kp >> 3);
        int c = (g - row * (Kp >> 3)) << 3;
        const float* s = src + (size_t)row * K + c;
        u16x8 v;
        if (c + 8 <= K) {
#pragma unroll
            for (int j = 0; j < 4; ++j) {            // 8B-aligned (K,c even)
                float2 f = *(const float2*)(s + 2 * j);
                v[2*j] = f2bf(f.x); v[2*j+1] = f2bf(f.y);
            }
        } else {
#pragma unroll
            for (int j = 0; j < 8; ++j) v[j] = (c + j < K) ? f2bf(s[j]) : (unsigned short)0;
        }
        *(u16x8*)(dst + (size_t)row * Kp + c) = v;
    }
}

// ---------------- router scores: one wave per token row ----------------
__global__ __launch_bounds__(256) void k_router(const float* __restrict__ x,
                                                const float* __restrict__ wr,
                                                float* __restrict__ sc) {
    int gw   = (blockIdx.x * 256 + threadIdx.x) >> 6;   // 0..B*T-1
    int lane = threadIdx.x & 63;
    const float* row = x + (size_t)gw * D_;
    float s = 0.f;
#pragma unroll
    for (int p = 0; p < 4; ++p) {
        int c = p * 256 + lane * 4;
        float4 xv = *(const float4*)(row + c);
        float4 wv = *(const float4*)(wr + c);
        s += xv.x * wv.x + xv.y * wv.y + xv.z * wv.z + xv.w * wv.w;
    }
#pragma unroll
    for (int o = 32; o; o >>= 1) s += __shfl_xor(s, o);
    if (lane == 0) sc[gw] = s;
}

// ---------------- exact top-k: bitonic sort 4096 keys per batch (256 thr) ----------------
__global__ __launch_bounds__(256) void k_topk(const float* __restrict__ sc,
                                              int* __restrict__ idx) {
    __shared__ unsigned long long keys[T_];
    const float* s = sc + (size_t)blockIdx.x * T_;
    for (int i = threadIdx.x; i < T_; i += 256) {
        union { float f; unsigned int u; } v; v.f = s[i];
        unsigned int k = (v.u & 0x80000000u) ? ~v.u : (v.u | 0x80000000u);
        k = ~k;
        keys[i] = ((unsigned long long)k << 32) | (unsigned int)i;
    }
    __syncthreads();
    for (int kk = 2; kk <= T_; kk <<= 1) {
        for (int j = kk >> 1; j > 0; j >>= 1) {
            for (int i = threadIdx.x; i < T_; i += 256) {
                int ixj = i ^ j;
                if (ixj > i) {
                    unsigned long long a = keys[i], b = keys[ixj];
                    bool up = ((i & kk) == 0);
                    if ((a > b) == up) { keys[i] = b; keys[ixj] = a; }
                }
            }
            __syncthreads();
        }
    }
    for (int i = threadIdx.x; i < CAP_; i += 256)
        idx[blockIdx.x * CAP_ + i] = (int)(keys[i] & 0xffffffffu);
}

// ---------------- gather + RMSNorm(g1) -> h (bf16) ----------------
__global__ __launch_bounds__(256) void k_gather_rms(const float* __restrict__ x,
                                                    const int* __restrict__ idx,
                                                    const float* __restrict__ g,
                                                    unsigned short* __restrict__ h) {
    int r = blockIdx.x;                 // 0..M_-1
    int b = r >> 9;                     // /CAP_
    int src = idx[r] & (T_ - 1);
    const float* xr = x + ((size_t)b * T_ + src) * D_;
    int c = threadIdx.x * 4;
    float4 xv = *(const float4*)(xr + c);
    float ss = xv.x*xv.x + xv.y*xv.y + xv.z*xv.z + xv.w*xv.w;
#pragma unroll
    for (int o = 32; o; o >>= 1) ss += __shfl_xor(ss, o);
    __shared__ float red[4];
    int lane = threadIdx.x & 63, w = threadIdx.x >> 6;
    if (lane == 0) red[w] = ss;
    __syncthreads();
    float tot = red[0] + red[1] + red[2] + red[3];
    float scale = rsqrtf(tot * (1.f / D_) + 1e-6f);
    float4 gv = *(const float4*)(g + c);
    ushort4 hv;
    hv.x = f2bf(xv.x * scale * gv.x);
    hv.y = f2bf(xv.y * scale * gv.y);
    hv.z = f2bf(xv.z * scale * gv.z);
    hv.w = f2bf(xv.w * scale * gv.w);
    *(ushort4*)(h + (size_t)r * D_ + c) = hv;
}

// ---------------- MFMA GEMM 64x128 (BK=64), global_load_lds + XOR swizzle ----------------
// C[M,Nout] = A[M,Kr] * B[Nrows,Kr]^T. A,B bf16. Kr % 64 == 0. B rows padded to
// the 128-tile multiple with zeros (no staging guard). LDS linear (gload_lds
// requirement); 16B-block swizzle: phys_blk = logical_blk ^ (row & 7), applied
// on the GLOBAL source (inverse) and the ds_read address — rule #21.
// 4 waves split N (each 64x32: 4x2 frags, 16 MFMA/K-iter).
// EPI==1: C = silu(U) * acc (U may alias C; 1:1 thread:element).
template<int EPI>
__global__ __launch_bounds__(256) void k_gemm64g(const unsigned short* __restrict__ A,
                                                 const unsigned short* __restrict__ Bw,
                                                 unsigned short* __restrict__ C,
                                                 const unsigned short* __restrict__ U,
                                                 int Nout, int Kr) {
    __shared__ __align__(16) unsigned short As[64 * 64];    // linear, 8KB
    __shared__ __align__(16) unsigned short Bs[128 * 64];   // linear, 16KB
    int m0 = blockIdx.x * 64;
    int n0 = blockIdx.y * 128;
    int t = threadIdx.x;
    int w = t >> 6, lane = t & 63;
    int lr = lane & 15, lg = lane >> 4;
    int l8 = lane >> 3, lm8 = lane & 7;

    f32x4 acc[4][2];
#pragma unroll
    for (int mi = 0; mi < 4; ++mi)
#pragma unroll
        for (int ni = 0; ni < 2; ++ni) acc[mi][ni] = {0.f, 0.f, 0.f, 0.f};

    for (int k0 = 0; k0 < Kr; k0 += 64) {
        // A tile 64x64: wave w rows 16w..16w+15 (2 insts x 8 rows)
#pragma unroll
        for (int j = 0; j < 2; ++j) {
            int r0 = w * 16 + j * 8;
            int row = r0 + l8;
            int cb = lm8 ^ (row & 7);
            gload_lds16(A + (size_t)(m0 + row) * Kr + k0 + cb * 8, &As[r0 * 64]);
        }
        // B tile 128x64: wave w rows 32w..32w+31 (4 insts x 8 rows)
#pragma unroll
        for (int j = 0; j < 4; ++j) {
            int r0 = w * 32 + j * 8;
            int row = r0 + l8;
            int cb = lm8 ^ (row & 7);
            gload_lds16(Bw + (size_t)(n0 + row) * Kr + k0 + cb * 8, &Bs[r0 * 64]);
        }
        __syncthreads();   // compiler drains vmcnt(0) before s_barrier
#pragma unroll
        for (int kh = 0; kh < 2; ++kh) {
            s16x8 af[4], bf[2];
#pragma unroll
            for (int i = 0; i < 4; ++i) {
                int row = i * 16 + lr;
                int pb = (kh * 4 + lg) ^ (row & 7);
                af[i] = *(const s16x8*)&As[row * 64 + pb * 8];
            }
#pragma unroll
            for (int i = 0; i < 2; ++i) {
                int row = w * 32 + i * 16 + lr;
                int pb = (kh * 4 + lg) ^ (row & 7);
                bf[i] = *(const s16x8*)&Bs[row * 64 + pb * 8];
            }
#pragma unroll
            for (int mi = 0; mi < 4; ++mi)
#pragma unroll
                for (int ni = 0; ni < 2; ++ni)
                    acc[mi][ni] = __builtin_amdgcn_mfma_f32_16x16x32_bf16(af[mi], bf[ni],
                                                                          acc[mi][ni], 0, 0, 0);
        }
        __syncthreads();
    }
    // C/D layout: row = (lane>>4)*4 + i, col = lane&15  [measured m89]
    int orow0 = m0 + (lg << 2);
    int ocol0 = n0 + w * 32 + lr;
#pragma unroll
    for (int ni = 0; ni < 2; ++ni) {
        int col = ocol0 + ni * 16;
        if (col < Nout) {
#pragma unroll
            for (int mi = 0; mi < 4; ++mi) {
#pragma unroll
                for (int i = 0; i < 4; ++i) {
                    size_t ci = (size_t)(orow0 + mi * 16 + i) * Nout + col;
                    if (EPI == 1) {
                        float uv = bf2f(U[ci]);
                        float sl = uv / (1.f + __expf(-uv));
                        C[ci] = f2bf(sl * acc[mi][ni][i]);
                    } else {
                        C[ci] = f2bf(acc[mi][ni][i]);
                    }
                }
            }
        }
    }
}

// ---------------- MFMA flash attention (causal, gathered order) ----------------
// One workgroup per (qtile=64, head, batch); 4 waves x 16 q-rows.
__global__ __launch_bounds__(256) void k_attn_mfma(const unsigned short* __restrict__ qkv,
                                                   unsigned short* __restrict__ o) {
    __shared__ __align__(16) unsigned short Ks[32][72];     // [kv][hd 0..63]
    __shared__ __align__(16) unsigned short Vt[64][40];     // [d][kv 0..31]
    __shared__ __align__(16) unsigned short Ps[4][16][40];  // per-wave P [q][kv]
    int qt = blockIdx.x, h = blockIdx.y, b = blockIdx.z;
    int q0 = qt * 64;
    int t = threadIdx.x, w = t >> 6, lane = t & 63;
    int lr = lane & 15, lg = lane >> 4;
    const unsigned short* base = qkv + (size_t)b * CAP_ * 3 * D_;

    int qrow = q0 + w * 16 + lr;
    const unsigned short* qp = base + (size_t)qrow * 3 * D_ + h * 64;
    s16x8 aq0 = *(const s16x8*)(qp + lg * 8);
    s16x8 aq1 = *(const s16x8*)(qp + 32 + lg * 8);

    f32x4 zero = {0.f, 0.f, 0.f, 0.f};
    f32x4 oacc[4] = {zero, zero, zero, zero};
    float m_[4], l_[4];
#pragma unroll
    for (int i = 0; i < 4; ++i) { m_[i] = -3.0e38f; l_[i] = 0.f; }

    int qbase = q0 + w * 16 + lg * 4;
    int ntile = (q0 + 64) >> 5;

    int skv = t >> 3, sc = (t & 7) * 8;
    for (int kt = 0; kt < ntile; ++kt) {
        int kv0 = kt << 5;
        {
            const unsigned short* kr = base + (size_t)(kv0 + skv) * 3 * D_ + D_     + h * 64 + sc;
            const unsigned short* vr = base + (size_t)(kv0 + skv) * 3 * D_ + 2 * D_ + h * 64 + sc;
            *(u16x8*)&Ks[skv][sc] = *(const u16x8*)kr;
            u16x8 vv = *(const u16x8*)vr;
#pragma unroll
            for (int j = 0; j < 8; ++j) Vt[sc + j][skv] = vv[j];
        }
        __syncthreads();
        f32x4 s0 = zero, s1 = zero;
        s16x8 k00 = *(const s16x8*)&Ks[lr][lg * 8];
        s16x8 k01 = *(const s16x8*)&Ks[lr][32 + lg * 8];
        s16x8 k10 = *(const s16x8*)&Ks[16 + lr][lg * 8];
        s16x8 k11 = *(const s16x8*)&Ks[16 + lr][32 + lg * 8];
        s0 = __builtin_amdgcn_mfma_f32_16x16x32_bf16(aq0, k00, s0, 0, 0, 0);
        s0 = __builtin_amdgcn_mfma_f32_16x16x32_bf16(aq1, k01, s0, 0, 0, 0);
        s1 = __builtin_amdgcn_mfma_f32_16x16x32_bf16(aq0, k10, s1, 0, 0, 0);
        s1 = __builtin_amdgcn_mfma_f32_16x16x32_bf16(aq1, k11, s1, 0, 0, 0);
#pragma unroll
        for (int i = 0; i < 4; ++i) {
            float v0 = s0[i] * 0.125f, v1 = s1[i] * 0.125f;
            if (kv0 + lr      > qbase + i) v0 = -3.0e38f;
            if (kv0 + 16 + lr > qbase + i) v1 = -3.0e38f;
            s0[i] = v0; s1[i] = v1;
        }
        float pm[4];
#pragma unroll
        for (int i = 0; i < 4; ++i) pm[i] = fmaxf(s0[i], s1[i]);
#pragma unroll
        for (int d = 1; d < 16; d <<= 1) {
#pragma unroll
            for (int i = 0; i < 4; ++i) pm[i] = fmaxf(pm[i], __shfl_xor(pm[i], d));
        }
        float p0[4], p1[4], ps[4], scl[4];
#pragma unroll
        for (int i = 0; i < 4; ++i) {
            float mn = fmaxf(m_[i], pm[i]);
            scl[i] = __expf(m_[i] - mn);
            p0[i] = __expf(s0[i] - mn);
            p1[i] = __expf(s1[i] - mn);
            ps[i] = p0[i] + p1[i];
            m_[i] = mn;
        }
#pragma unroll
        for (int d = 1; d < 16; d <<= 1) {
#pragma unroll
            for (int i = 0; i < 4; ++i) ps[i] += __shfl_xor(ps[i], d);
        }
#pragma unroll
        for (int i = 0; i < 4; ++i) l_[i] = l_[i] * scl[i] + ps[i];
#pragma unroll
        for (int dg = 0; dg < 4; ++dg)
#pragma unroll
            for (int i = 0; i < 4; ++i) oacc[dg][i] *= scl[i];
#pragma unroll
        for (int i = 0; i < 4; ++i) {
            Ps[w][lg * 4 + i][lr]      = f2bf(p0[i]);
            Ps[w][lg * 4 + i][16 + lr] = f2bf(p1[i]);
        }
        __syncthreads();
        s16x8 pa = *(const s16x8*)&Ps[w][lr][lg * 8];
#pragma unroll
        for (int dg = 0; dg < 4; ++dg) {
            s16x8 vf = *(const s16x8*)&Vt[dg * 16 + lr][lg * 8];
            oacc[dg] = __builtin_amdgcn_mfma_f32_16x16x32_bf16(pa, vf, oacc[dg], 0, 0, 0);
        }
        __syncthreads();
    }
    unsigned short* orow = o + ((size_t)(b * CAP_ + qbase)) * D_ + h * 64;
#pragma unroll
    for (int i = 0; i < 4; ++i) {
        float inv = 1.f / l_[i];
#pragma unroll
        for (int dg = 0; dg < 4; ++dg)
            orow[(size_t)i * D_ + dg * 16 + lr] = f2bf(oacc[dg][i] * inv);
    }
}

// ---------------- y = x_sel + xattn; h2 = rmsnorm(y, g2) ----------------
__global__ __launch_bounds__(256) void k_add_rms(const float* __restrict__ x,
                                                 const int* __restrict__ idx,
                                                 const unsigned short* __restrict__ xattn,
                                                 const float* __restrict__ g,
                                                 unsigned short* __restrict__ y,
                                                 unsigned short* __restrict__ h) {
    int r = blockIdx.x;
    int b = r >> 9;
    int src = idx[r] & (T_ - 1);
    int c = threadIdx.x * 4;
    const float* xr = x + ((size_t)b * T_ + src) * D_;
    float4 xv = *(const float4*)(xr + c);
    size_t off = (size_t)r * D_ + c;
    ushort4 a4 = *(const ushort4*)(xattn + off);
    float v0 = xv.x + bf2f(a4.x);
    float v1 = xv.y + bf2f(a4.y);
    float v2 = xv.z + bf2f(a4.z);
    float v3 = xv.w + bf2f(a4.w);
    float ss = v0*v0 + v1*v1 + v2*v2 + v3*v3;
#pragma unroll
    for (int o = 32; o; o >>= 1) ss += __shfl_xor(ss, o);
    __shared__ float red[4];
    int lane = threadIdx.x & 63, w = threadIdx.x >> 6;
    if (lane == 0) red[w] = ss;
    __syncthreads();
    float tot = red[0] + red[1] + red[2] + red[3];
    float scale = rsqrtf(tot * (1.f / D_) + 1e-6f);
    ushort4 yv;
    yv.x = f2bf(v0); yv.y = f2bf(v1); yv.z = f2bf(v2); yv.w = f2bf(v3);
    *(ushort4*)(y + off) = yv;
    float4 gv = *(const float4*)(g + c);
    ushort4 hv;
    hv.x = f2bf(v0 * scale * gv.x);
    hv.y = f2bf(v1 * scale * gv.y);
    hv.z = f2bf(v2 * scale * gv.z);
    hv.w = f2bf(v3 * scale * gv.w);
    *(ushort4*)(h + off) = hv;
}

// ---------------- scatter: out[b, idx, :] = y + xff  (fp32 out) ----------------
__global__ __launch_bounds__(256) void k_scatter(const unsigned short* __restrict__ y,
                                                 const unsigned short* __restrict__ xff,
                                                 const int* __restrict__ idx,
                                                 float* __restrict__ out) {
    int r = blockIdx.x;
    int b = r >> 9;
    int dst = idx[r] & (T_ - 1);
    int c = threadIdx.x * 4;
    size_t src = (size_t)r * D_ + c;
    ushort4 a4 = *(const ushort4*)(y + src);
    ushort4 f4 = *(const ushort4*)(xff + src);
    float4 o4;
    o4.x = bf2f(a4.x) + bf2f(f4.x);
    o4.y = bf2f(a4.y) + bf2f(f4.y);
    o4.z = bf2f(a4.z) + bf2f(f4.z);
    o4.w = bf2f(a4.w) + bf2f(f4.w);
    *(float4*)(out + ((size_t)b * T_ + dst) * D_ + c) = o4;
}

extern "C" void kernel_launch(void* const* d_in, const int* in_sizes, int n_in,
                              void* d_out, int out_size, void* d_ws, size_t ws_size,
                              hipStream_t stream) {
    const float* x     = (const float*)d_in[0];
    const float* w_rt  = (const float*)d_in[1];
    const float* W_qkv = (const float*)d_in[2];
    const float* W_out = (const float*)d_in[3];
    const float* g1    = (const float*)d_in[4];
    const float* g2    = (const float*)d_in[5];
    const float* W1    = (const float*)d_in[6];
    const float* W2    = (const float*)d_in[7];
    const float* W3    = (const float*)d_in[8];
    float* out = (float*)d_out;

    // ---- workspace: ~31.6 MiB (layout identical to r12/r13) ----
    char* p = (char*)d_ws;
    float* scores = (float*)p;
    int*   idx    = (int*)(p + 65536);
    size_t off = 131072;
    unsigned short* WBIG = (unsigned short*)(p + off); off += (size_t)3*D_*D_*2;   // 6.29M
    unsigned short* R1   = (unsigned short*)(p + off); off += (size_t)M_*3*D_*2;   // 12.58M
    unsigned short* R2   = (unsigned short*)(p + off); off += (size_t)M_*D_*2;     // 4.19M
    unsigned short* R3   = (unsigned short*)(p + off); off += (size_t)M_*D_*2;     // 4.19M
    unsigned short* R4   = (unsigned short*)(p + off); off += (size_t)M_*D_*2;     // 4.19M

    unsigned short* h1    = R2;
    unsigned short* qkvb  = R1;
    unsigned short* attno = R2;   // after h1 dead
    unsigned short* xattn = R3;
    unsigned short* ybuf  = R4;
    unsigned short* h2b   = R2;   // after attno dead
    unsigned short* ubuf  = R1;   // after qkvb dead; [2048][DFFP]
    unsigned short* xffb  = R3;   // after xattn dead

    // 1. out = x  (fp32 pass-through; selected rows overwritten by scatter)
    k_copyf<<<2048, 256, 0, stream>>>((const float4*)x, (float4*)out, (B_*T_*D_) / 4);
    // 2. router scores
    k_router<<<(B_*T_) / 4, 256, 0, stream>>>(x, w_rt, scores);
    // 3. exact top-k (256 threads: 4-wave barriers)
    k_topk<<<B_, 256, 0, stream>>>(scores, idx);
    // 4. gather + rmsnorm(g1) -> h1 (bf16)
    k_gather_rms<<<M_, 256, 0, stream>>>(x, idx, g1, h1);
    // 5. qkv = h1 @ W_qkv^T   [2048 x 3072], K=1024   (768 blocks)
    k_f2b<<<2048, 256, 0, stream>>>((const float4*)W_qkv, (ushort4*)WBIG, (3*D_*D_) / 4);
    k_gemm64g<0><<<dim3(M_/64, 3*D_/128), 256, 0, stream>>>(h1, WBIG, qkvb, nullptr,
                                                            3*D_, D_);
    // 6. MFMA flash attention
    k_attn_mfma<<<dim3(CAP_/64, H_, B_), 256, 0, stream>>>(qkvb, attno);
    // 7. x_attn = o @ W_out^T  [2048 x 1024], K=1024   (256 blocks)
    k_f2b<<<1024, 256, 0, stream>>>((const float4*)W_out, (ushort4*)WBIG, (D_*D_) / 4);
    k_gemm64g<0><<<dim3(M_/64, D_/128), 256, 0, stream>>>(attno, WBIG, xattn, nullptr,
                                                          D_, D_);
    // 8. y = x_sel + xattn; h2 = rmsnorm(y, g2)
    k_add_rms<<<M_, 256, 0, stream>>>(x, idx, xattn, g2, ybuf, h2b);
    // 9. u = h2 @ W1^T  -> ubuf [2048][DFFP]; WBIG rows padded to DFFR w/ zeros
    k_f2b_rowpad<<<2048, 256, 0, stream>>>(W1, WBIG, D_/8, DFF_, DFFR*(D_/8));
    k_gemm64g<0><<<dim3(M_/64, DFFR/128), 256, 0, stream>>>(h2b, WBIG, ubuf, nullptr,
                                                            DFFP, D_);
    // 10. f = silu(u) * (h2 @ W2^T)  — fused epilogue, in-place into ubuf
    k_f2b_rowpad<<<2048, 256, 0, stream>>>(W2, WBIG, D_/8, DFF_, DFFR*(D_/8));
    k_gemm64g<1><<<dim3(M_/64, DFFR/128), 256, 0, stream>>>(h2b, WBIG, ubuf, ubuf,
                                                            DFFP, D_);
    // 11. x_ff = f @ W3^T   [2048 x 1024], K=DFFP (pad cols zero both sides)
    k_f2b_pad<<<2048, 256, 0, stream>>>(W3, WBIG, DFF_, DFFP, D_);
    k_gemm64g<0><<<dim3(M_/64, D_/128), 256, 0, stream>>>(ubuf, WBIG, xffb, nullptr,
                                                          D_, DFFP);
    // 12. out[b, idx, :] = y + x_ff  (fp32)
    k_scatter<<<M_, 256, 0, stream>>>(ybuf, xffb, idx, out);
}

// Round 15
// 263.721 us; speedup vs baseline: 1.3478x; 1.3478x over previous
//
#include <hip/hip_runtime.h>
#include <hip/hip_bf16.h>

// MoD transformer block: B=4, T=4096, D=1024, H=16, HD=64, CAP=512, DFF=2730
// Inputs fp32, output fp32. Round 15:
//  (a) topk reverted to 1024 threads (r14's 256-thr was 57->138 regression).
//  (b) W1/W2 GEMMs fused: one kernel, two B tiles, two acc sets, epilogue
//      f = silu(accU)*accG — kills 22MB of ubuf round-trip + one dispatch.

#define B_   4
#define T_   4096
#define D_   1024
#define H_   16
#define HD_  64
#define CAP_ 512
#define DFF_ 2730
#define DFFP 2752               // DFF padded to mult of 64 (K-path)
#define DFFR 2816               // DFF padded to mult of 128 (B-row tiles)
#define M_   (B_*CAP_)          // 2048 selected rows total

typedef __attribute__((ext_vector_type(8))) short          s16x8;
typedef __attribute__((ext_vector_type(8))) unsigned short u16x8;
typedef __attribute__((ext_vector_type(4))) float          f32x4;

__device__ __forceinline__ float bf2f(unsigned short u) {
    union { float f; unsigned int i; } v; v.i = ((unsigned int)u) << 16; return v.f;
}
__device__ __forceinline__ unsigned short f2bf(float f) {
    union { float f; unsigned int i; } v; v.f = f;
    unsigned int r = v.i + 0x7fffu + ((v.i >> 16) & 1u);   // RNE
    return (unsigned short)(r >> 16);
}

// async global->LDS, 16B per lane; LDS dest = wave-uniform base + lane*16
__device__ __forceinline__ void gload_lds16(const unsigned short* g, unsigned short* l) {
    __builtin_amdgcn_global_load_lds(
        (const __attribute__((address_space(1))) unsigned int*)g,
        (__attribute__((address_space(3))) unsigned int*)l, 16, 0, 0);
}

// ---------------- out = x pass-through (fp32 copy) ----------------
__global__ __launch_bounds__(256) void k_copyf(const float4* __restrict__ s,
                                               float4* __restrict__ d, int n4) {
    int i = blockIdx.x * 256 + threadIdx.x;
    int st = gridDim.x * 256;
    for (; i < n4; i += st) d[i] = s[i];
}

// ---------------- fp32 -> bf16 flat convert ----------------
__global__ __launch_bounds__(256) void k_f2b(const float4* __restrict__ s,
                                             ushort4* __restrict__ d, int n4) {
    int i = blockIdx.x * 256 + threadIdx.x;
    int st = gridDim.x * 256;
    for (; i < n4; i += st) {
        float4 v = s[i];
        ushort4 o;
        o.x = f2bf(v.x); o.y = f2bf(v.y); o.z = f2bf(v.z); o.w = f2bf(v.w);
        d[i] = o;
    }
}

// ---------------- fp32 [rows][K] -> bf16 [rowsP][K], pad ROWS zeroed ----------------
__global__ __launch_bounds__(256) void k_f2b_rowpad(const float* __restrict__ src,
                                                    unsigned short* __restrict__ dst,
                                                    int kc, int rows, int total) {
    int g = blockIdx.x * 256 + threadIdx.x;
    int st = gridDim.x * 256;
    for (; g < total; g += st) {
        int row = g / kc;
        u16x8 v = {0, 0, 0, 0, 0, 0, 0, 0};
        if (row < rows) {
            const float* s = src + ((size_t)g) * 8;
#pragma unroll
            for (int j = 0; j < 2; ++j) {
                float4 f = *(const float4*)(s + 4 * j);
                v[4*j]   = f2bf(f.x); v[4*j+1] = f2bf(f.y);
                v[4*j+2] = f2bf(f.z); v[4*j+3] = f2bf(f.w);
            }
        }
        *(u16x8*)(dst + (size_t)g * 8) = v;
    }
}

// ---------------- fp32 [rows][K] -> bf16 [rows][Kp], pad COLS zeroed ----------------
__global__ __launch_bounds__(256) void k_f2b_pad(const float* __restrict__ src,
                                                 unsigned short* __restrict__ dst,
                                                 int K, int Kp, int rows) {
    int g = blockIdx.x * 256 + threadIdx.x;
    int ng = rows * (Kp >> 3);
    int st = gridDim.x * 256;
    for (; g < ng; g += st) {
        int row = g / (Kp >> 3);
        int c = (g - row * (Kp >> 3)) << 3;
        const float* s = src + (size_t)row * K + c;
        u16x8 v;
        if (c + 8 <= K) {
#pragma unroll
            for (int j = 0; j < 4; ++j) {            // 8B-aligned (K,c even)
                float2 f = *(const float2*)(s + 2 * j);
                v[2*j] = f2bf(f.x); v[2*j+1] = f2bf(f.y);
            }
        } else {
#pragma unroll
            for (int j = 0; j < 8; ++j) v[j] = (c + j < K) ? f2bf(s[j]) : (unsigned short)0;
        }
        *(u16x8*)(dst + (size_t)row * Kp + c) = v;
    }
}

// ---------------- router scores: one wave per token row ----------------
__global__ __launch_bounds__(256) void k_router(const float* __restrict__ x,
                                                const float* __restrict__ wr,
                                                float* __restrict__ sc) {
    int gw   = (blockIdx.x * 256 + threadIdx.x) >> 6;   // 0..B*T-1
    int lane = threadIdx.x & 63;
    const float* row = x + (size_t)gw * D_;
    float s = 0.f;
#pragma unroll
    for (int p = 0; p < 4; ++p) {
        int c = p * 256 + lane * 4;
        float4 xv = *(const float4*)(row + c);
        float4 wv = *(const float4*)(wr + c);
        s += xv.x * wv.x + xv.y * wv.y + xv.z * wv.z + xv.w * wv.w;
    }
#pragma unroll
    for (int o = 32; o; o >>= 1) s += __shfl_xor(s, o);
    if (lane == 0) sc[gw] = s;
}

// ---------------- exact top-k: bitonic sort 4096 keys per batch (1024 thr) ----------------
__global__ __launch_bounds__(1024) void k_topk(const float* __restrict__ sc,
                                               int* __restrict__ idx) {
    __shared__ unsigned long long keys[T_];
    const float* s = sc + (size_t)blockIdx.x * T_;
    for (int i = threadIdx.x; i < T_; i += 1024) {
        union { float f; unsigned int u; } v; v.f = s[i];
        unsigned int k = (v.u & 0x80000000u) ? ~v.u : (v.u | 0x80000000u);
        k = ~k;
        keys[i] = ((unsigned long long)k << 32) | (unsigned int)i;
    }
    __syncthreads();
    for (int kk = 2; kk <= T_; kk <<= 1) {
        for (int j = kk >> 1; j > 0; j >>= 1) {
            for (int i = threadIdx.x; i < T_; i += 1024) {
                int ixj = i ^ j;
                if (ixj > i) {
                    unsigned long long a = keys[i], b = keys[ixj];
                    bool up = ((i & kk) == 0);
                    if ((a > b) == up) { keys[i] = b; keys[ixj] = a; }
                }
            }
            __syncthreads();
        }
    }
    for (int i = threadIdx.x; i < CAP_; i += 1024)
        idx[blockIdx.x * CAP_ + i] = (int)(keys[i] & 0xffffffffu);
}

// ---------------- gather + RMSNorm(g1) -> h (bf16) ----------------
__global__ __launch_bounds__(256) void k_gather_rms(const float* __restrict__ x,
                                                    const int* __restrict__ idx,
                                                    const float* __restrict__ g,
                                                    unsigned short* __restrict__ h) {
    int r = blockIdx.x;                 // 0..M_-1
    int b = r >> 9;                     // /CAP_
    int src = idx[r] & (T_ - 1);
    const float* xr = x + ((size_t)b * T_ + src) * D_;
    int c = threadIdx.x * 4;
    float4 xv = *(const float4*)(xr + c);
    float ss = xv.x*xv.x + xv.y*xv.y + xv.z*xv.z + xv.w*xv.w;
#pragma unroll
    for (int o = 32; o; o >>= 1) ss += __shfl_xor(ss, o);
    __shared__ float red[4];
    int lane = threadIdx.x & 63, w = threadIdx.x >> 6;
    if (lane == 0) red[w] = ss;
    __syncthreads();
    float tot = red[0] + red[1] + red[2] + red[3];
    float scale = rsqrtf(tot * (1.f / D_) + 1e-6f);
    float4 gv = *(const float4*)(g + c);
    ushort4 hv;
    hv.x = f2bf(xv.x * scale * gv.x);
    hv.y = f2bf(xv.y * scale * gv.y);
    hv.z = f2bf(xv.z * scale * gv.z);
    hv.w = f2bf(xv.w * scale * gv.w);
    *(ushort4*)(h + (size_t)r * D_ + c) = hv;
}

// ---------------- MFMA GEMM 64x128 (BK=64), global_load_lds + XOR swizzle ----------------
// C[M,Nout] = A[M,Kr] * B[Nrows,Kr]^T. B rows padded to 128-tile mult (no guard).
__global__ __launch_bounds__(256) void k_gemm64g(const unsigned short* __restrict__ A,
                                                 const unsigned short* __restrict__ Bw,
                                                 unsigned short* __restrict__ C,
                                                 int Nout, int Kr) {
    __shared__ __align__(16) unsigned short As[64 * 64];    // linear, 8KB
    __shared__ __align__(16) unsigned short Bs[128 * 64];   // linear, 16KB
    int m0 = blockIdx.x * 64;
    int n0 = blockIdx.y * 128;
    int t = threadIdx.x;
    int w = t >> 6, lane = t & 63;
    int lr = lane & 15, lg = lane >> 4;
    int l8 = lane >> 3, lm8 = lane & 7;

    f32x4 acc[4][2];
#pragma unroll
    for (int mi = 0; mi < 4; ++mi)
#pragma unroll
        for (int ni = 0; ni < 2; ++ni) acc[mi][ni] = {0.f, 0.f, 0.f, 0.f};

    for (int k0 = 0; k0 < Kr; k0 += 64) {
#pragma unroll
        for (int j = 0; j < 2; ++j) {
            int r0 = w * 16 + j * 8;
            int row = r0 + l8;
            int cb = lm8 ^ (row & 7);
            gload_lds16(A + (size_t)(m0 + row) * Kr + k0 + cb * 8, &As[r0 * 64]);
        }
#pragma unroll
        for (int j = 0; j < 4; ++j) {
            int r0 = w * 32 + j * 8;
            int row = r0 + l8;
            int cb = lm8 ^ (row & 7);
            gload_lds16(Bw + (size_t)(n0 + row) * Kr + k0 + cb * 8, &Bs[r0 * 64]);
        }
        __syncthreads();
#pragma unroll
        for (int kh = 0; kh < 2; ++kh) {
            s16x8 af[4], bf[2];
#pragma unroll
            for (int i = 0; i < 4; ++i) {
                int row = i * 16 + lr;
                int pb = (kh * 4 + lg) ^ (row & 7);
                af[i] = *(const s16x8*)&As[row * 64 + pb * 8];
            }
#pragma unroll
            for (int i = 0; i < 2; ++i) {
                int row = w * 32 + i * 16 + lr;
                int pb = (kh * 4 + lg) ^ (row & 7);
                bf[i] = *(const s16x8*)&Bs[row * 64 + pb * 8];
            }
#pragma unroll
            for (int mi = 0; mi < 4; ++mi)
#pragma unroll
                for (int ni = 0; ni < 2; ++ni)
                    acc[mi][ni] = __builtin_amdgcn_mfma_f32_16x16x32_bf16(af[mi], bf[ni],
                                                                          acc[mi][ni], 0, 0, 0);
        }
        __syncthreads();
    }
    int orow0 = m0 + (lg << 2);
    int ocol0 = n0 + w * 32 + lr;
#pragma unroll
    for (int ni = 0; ni < 2; ++ni) {
        int col = ocol0 + ni * 16;
        if (col < Nout) {
#pragma unroll
            for (int mi = 0; mi < 4; ++mi)
#pragma unroll
                for (int i = 0; i < 4; ++i)
                    C[(size_t)(orow0 + mi * 16 + i) * Nout + col] = f2bf(acc[mi][ni][i]);
        }
    }
}

// ---------------- FUSED W1/W2 GEMM: F = silu(A*B1^T) * (A*B2^T) ----------------
// Same structure; two B tiles, two acc sets, 32 MFMA/wave/K-step. LDS 40KB.
__global__ __launch_bounds__(256) void k_gemm64g2(const unsigned short* __restrict__ A,
                                                  const unsigned short* __restrict__ B1,
                                                  const unsigned short* __restrict__ B2,
                                                  unsigned short* __restrict__ F,
                                                  int Nout, int Kr) {
    __shared__ __align__(16) unsigned short As[64 * 64];     // 8KB
    __shared__ __align__(16) unsigned short B1s[128 * 64];   // 16KB
    __shared__ __align__(16) unsigned short B2s[128 * 64];   // 16KB
    int m0 = blockIdx.x * 64;
    int n0 = blockIdx.y * 128;
    int t = threadIdx.x;
    int w = t >> 6, lane = t & 63;
    int lr = lane & 15, lg = lane >> 4;
    int l8 = lane >> 3, lm8 = lane & 7;

    f32x4 accU[4][2], accG[4][2];
#pragma unroll
    for (int mi = 0; mi < 4; ++mi)
#pragma unroll
        for (int ni = 0; ni < 2; ++ni) {
            accU[mi][ni] = {0.f, 0.f, 0.f, 0.f};
            accG[mi][ni] = {0.f, 0.f, 0.f, 0.f};
        }

    for (int k0 = 0; k0 < Kr; k0 += 64) {
#pragma unroll
        for (int j = 0; j < 2; ++j) {
            int r0 = w * 16 + j * 8;
            int row = r0 + l8;
            int cb = lm8 ^ (row & 7);
            gload_lds16(A + (size_t)(m0 + row) * Kr + k0 + cb * 8, &As[r0 * 64]);
        }
#pragma unroll
        for (int j = 0; j < 4; ++j) {
            int r0 = w * 32 + j * 8;
            int row = r0 + l8;
            int cb = lm8 ^ (row & 7);
            size_t goff = (size_t)(n0 + row) * Kr + k0 + cb * 8;
            gload_lds16(B1 + goff, &B1s[r0 * 64]);
            gload_lds16(B2 + goff, &B2s[r0 * 64]);
        }
        __syncthreads();
#pragma unroll
        for (int kh = 0; kh < 2; ++kh) {
            s16x8 af[4], b1f[2], b2f[2];
#pragma unroll
            for (int i = 0; i < 4; ++i) {
                int row = i * 16 + lr;
                int pb = (kh * 4 + lg) ^ (row & 7);
                af[i] = *(const s16x8*)&As[row * 64 + pb * 8];
            }
#pragma unroll
            for (int i = 0; i < 2; ++i) {
                int row = w * 32 + i * 16 + lr;
                int pb = (kh * 4 + lg) ^ (row & 7);
                b1f[i] = *(const s16x8*)&B1s[row * 64 + pb * 8];
                b2f[i] = *(const s16x8*)&B2s[row * 64 + pb * 8];
            }
#pragma unroll
            for (int mi = 0; mi < 4; ++mi)
#pragma unroll
                for (int ni = 0; ni < 2; ++ni) {
                    accU[mi][ni] = __builtin_amdgcn_mfma_f32_16x16x32_bf16(af[mi], b1f[ni],
                                                                           accU[mi][ni], 0, 0, 0);
                    accG[mi][ni] = __builtin_amdgcn_mfma_f32_16x16x32_bf16(af[mi], b2f[ni],
                                                                           accG[mi][ni], 0, 0, 0);
                }
        }
        __syncthreads();
    }
    int orow0 = m0 + (lg << 2);
    int ocol0 = n0 + w * 32 + lr;
#pragma unroll
    for (int ni = 0; ni < 2; ++ni) {
        int col = ocol0 + ni * 16;
        if (col < Nout) {
#pragma unroll
            for (int mi = 0; mi < 4; ++mi)
#pragma unroll
                for (int i = 0; i < 4; ++i) {
                    float u = accU[mi][ni][i];
                    float sl = u / (1.f + __expf(-u));
                    F[(size_t)(orow0 + mi * 16 + i) * Nout + col] = f2bf(sl * accG[mi][ni][i]);
                }
        }
    }
}

// ---------------- MFMA flash attention (causal, gathered order) ----------------
__global__ __launch_bounds__(256) void k_attn_mfma(const unsigned short* __restrict__ qkv,
                                                   unsigned short* __restrict__ o) {
    __shared__ __align__(16) unsigned short Ks[32][72];
    __shared__ __align__(16) unsigned short Vt[64][40];
    __shared__ __align__(16) unsigned short Ps[4][16][40];
    int qt = blockIdx.x, h = blockIdx.y, b = blockIdx.z;
    int q0 = qt * 64;
    int t = threadIdx.x, w = t >> 6, lane = t & 63;
    int lr = lane & 15, lg = lane >> 4;
    const unsigned short* base = qkv + (size_t)b * CAP_ * 3 * D_;

    int qrow = q0 + w * 16 + lr;
    const unsigned short* qp = base + (size_t)qrow * 3 * D_ + h * 64;
    s16x8 aq0 = *(const s16x8*)(qp + lg * 8);
    s16x8 aq1 = *(const s16x8*)(qp + 32 + lg * 8);

    f32x4 zero = {0.f, 0.f, 0.f, 0.f};
    f32x4 oacc[4] = {zero, zero, zero, zero};
    float m_[4], l_[4];
#pragma unroll
    for (int i = 0; i < 4; ++i) { m_[i] = -3.0e38f; l_[i] = 0.f; }

    int qbase = q0 + w * 16 + lg * 4;
    int ntile = (q0 + 64) >> 5;

    int skv = t >> 3, sc = (t & 7) * 8;
    for (int kt = 0; kt < ntile; ++kt) {
        int kv0 = kt << 5;
        {
            const unsigned short* kr = base + (size_t)(kv0 + skv) * 3 * D_ + D_     + h * 64 + sc;
            const unsigned short* vr = base + (size_t)(kv0 + skv) * 3 * D_ + 2 * D_ + h * 64 + sc;
            *(u16x8*)&Ks[skv][sc] = *(const u16x8*)kr;
            u16x8 vv = *(const u16x8*)vr;
#pragma unroll
            for (int j = 0; j < 8; ++j) Vt[sc + j][skv] = vv[j];
        }
        __syncthreads();
        f32x4 s0 = zero, s1 = zero;
        s16x8 k00 = *(const s16x8*)&Ks[lr][lg * 8];
        s16x8 k01 = *(const s16x8*)&Ks[lr][32 + lg * 8];
        s16x8 k10 = *(const s16x8*)&Ks[16 + lr][lg * 8];
        s16x8 k11 = *(const s16x8*)&Ks[16 + lr][32 + lg * 8];
        s0 = __builtin_amdgcn_mfma_f32_16x16x32_bf16(aq0, k00, s0, 0, 0, 0);
        s0 = __builtin_amdgcn_mfma_f32_16x16x32_bf16(aq1, k01, s0, 0, 0, 0);
        s1 = __builtin_amdgcn_mfma_f32_16x16x32_bf16(aq0, k10, s1, 0, 0, 0);
        s1 = __builtin_amdgcn_mfma_f32_16x16x32_bf16(aq1, k11, s1, 0, 0, 0);
#pragma unroll
        for (int i = 0; i < 4; ++i) {
            float v0 = s0[i] * 0.125f, v1 = s1[i] * 0.125f;
            if (kv0 + lr      > qbase + i) v0 = -3.0e38f;
            if (kv0 + 16 + lr > qbase + i) v1 = -3.0e38f;
            s0[i] = v0; s1[i] = v1;
        }
        float pm[4];
#pragma unroll
        for (int i = 0; i < 4; ++i) pm[i] = fmaxf(s0[i], s1[i]);
#pragma unroll
        for (int d = 1; d < 16; d <<= 1) {
#pragma unroll
            for (int i = 0; i < 4; ++i) pm[i] = fmaxf(pm[i], __shfl_xor(pm[i], d));
        }
        float p0[4], p1[4], ps[4], scl[4];
#pragma unroll
        for (int i = 0; i < 4; ++i) {
            float mn = fmaxf(m_[i], pm[i]);
            scl[i] = __expf(m_[i] - mn);
            p0[i] = __expf(s0[i] - mn);
            p1[i] = __expf(s1[i] - mn);
            ps[i] = p0[i] + p1[i];
            m_[i] = mn;
        }
#pragma unroll
        for (int d = 1; d < 16; d <<= 1) {
#pragma unroll
            for (int i = 0; i < 4; ++i) ps[i] += __shfl_xor(ps[i], d);
        }
#pragma unroll
        for (int i = 0; i < 4; ++i) l_[i] = l_[i] * scl[i] + ps[i];
#pragma unroll
        for (int dg = 0; dg < 4; ++dg)
#pragma unroll
            for (int i = 0; i < 4; ++i) oacc[dg][i] *= scl[i];
#pragma unroll
        for (int i = 0; i < 4; ++i) {
            Ps[w][lg * 4 + i][lr]      = f2bf(p0[i]);
            Ps[w][lg * 4 + i][16 + lr] = f2bf(p1[i]);
        }
        __syncthreads();
        s16x8 pa = *(const s16x8*)&Ps[w][lr][lg * 8];
#pragma unroll
        for (int dg = 0; dg < 4; ++dg) {
            s16x8 vf = *(const s16x8*)&Vt[dg * 16 + lr][lg * 8];
            oacc[dg] = __builtin_amdgcn_mfma_f32_16x16x32_bf16(pa, vf, oacc[dg], 0, 0, 0);
        }
        __syncthreads();
    }
    unsigned short* orow = o + ((size_t)(b * CAP_ + qbase)) * D_ + h * 64;
#pragma unroll
    for (int i = 0; i < 4; ++i) {
        float inv = 1.f / l_[i];
#pragma unroll
        for (int dg = 0; dg < 4; ++dg)
            orow[(size_t)i * D_ + dg * 16 + lr] = f2bf(oacc[dg][i] * inv);
    }
}

// ---------------- y = x_sel + xattn; h2 = rmsnorm(y, g2) ----------------
__global__ __launch_bounds__(256) void k_add_rms(const float* __restrict__ x,
                                                 const int* __restrict__ idx,
                                                 const unsigned short* __restrict__ xattn,
                                                 const float* __restrict__ g,
                                                 unsigned short* __restrict__ y,
                                                 unsigned short* __restrict__ h) {
    int r = blockIdx.x;
    int b = r >> 9;
    int src = idx[r] & (T_ - 1);
    int c = threadIdx.x * 4;
    const float* xr = x + ((size_t)b * T_ + src) * D_;
    float4 xv = *(const float4*)(xr + c);
    size_t off = (size_t)r * D_ + c;
    ushort4 a4 = *(const ushort4*)(xattn + off);
    float v0 = xv.x + bf2f(a4.x);
    float v1 = xv.y + bf2f(a4.y);
    float v2 = xv.z + bf2f(a4.z);
    float v3 = xv.w + bf2f(a4.w);
    float ss = v0*v0 + v1*v1 + v2*v2 + v3*v3;
#pragma unroll
    for (int o = 32; o; o >>= 1) ss += __shfl_xor(ss, o);
    __shared__ float red[4];
    int lane = threadIdx.x & 63, w = threadIdx.x >> 6;
    if (lane == 0) red[w] = ss;
    __syncthreads();
    float tot = red[0] + red[1] + red[2] + red[3];
    float scale = rsqrtf(tot * (1.f / D_) + 1e-6f);
    ushort4 yv;
    yv.x = f2bf(v0); yv.y = f2bf(v1); yv.z = f2bf(v2); yv.w = f2bf(v3);
    *(ushort4*)(y + off) = yv;
    float4 gv = *(const float4*)(g + c);
    ushort4 hv;
    hv.x = f2bf(v0 * scale * gv.x);
    hv.y = f2bf(v1 * scale * gv.y);
    hv.z = f2bf(v2 * scale * gv.z);
    hv.w = f2bf(v3 * scale * gv.w);
    *(ushort4*)(h + off) = hv;
}

// ---------------- scatter: out[b, idx, :] = y + xff  (fp32 out) ----------------
__global__ __launch_bounds__(256) void k_scatter(const unsigned short* __restrict__ y,
                                                 const unsigned short* __restrict__ xff,
                                                 const int* __restrict__ idx,
                                                 float* __restrict__ out) {
    int r = blockIdx.x;
    int b = r >> 9;
    int dst = idx[r] & (T_ - 1);
    int c = threadIdx.x * 4;
    size_t src = (size_t)r * D_ + c;
    ushort4 a4 = *(const ushort4*)(y + src);
    ushort4 f4 = *(const ushort4*)(xff + src);
    float4 o4;
    o4.x = bf2f(a4.x) + bf2f(f4.x);
    o4.y = bf2f(a4.y) + bf2f(f4.y);
    o4.z = bf2f(a4.z) + bf2f(f4.z);
    o4.w = bf2f(a4.w) + bf2f(f4.w);
    *(float4*)(out + ((size_t)b * T_ + dst) * D_ + c) = o4;
}

extern "C" void kernel_launch(void* const* d_in, const int* in_sizes, int n_in,
                              void* d_out, int out_size, void* d_ws, size_t ws_size,
                              hipStream_t stream) {
    const float* x     = (const float*)d_in[0];
    const float* w_rt  = (const float*)d_in[1];
    const float* W_qkv = (const float*)d_in[2];
    const float* W_out = (const float*)d_in[3];
    const float* g1    = (const float*)d_in[4];
    const float* g2    = (const float*)d_in[5];
    const float* W1    = (const float*)d_in[6];
    const float* W2    = (const float*)d_in[7];
    const float* W3    = (const float*)d_in[8];
    float* out = (float*)d_out;

    // ---- workspace: ~37 MiB ----
    // scores 64K | idx 8K | WBIG 11.54M (two DFFR x D bf16 weights / qkv 6.3M)
    // R1 12.58M (qkvb -> ubuf[2048][DFFP]) | R2 4.19M (h1 -> attno -> h2b)
    // R3 4.19M (xattn -> xffb) | R4 4.19M (ybuf)
    char* p = (char*)d_ws;
    float* scores = (float*)p;
    int*   idx    = (int*)(p + 65536);
    size_t off = 131072;
    const size_t WPAD = (size_t)DFFR * D_;                   // 2816*1024 elems
    unsigned short* WBIG = (unsigned short*)(p + off); off += 2 * WPAD * 2;       // 11.54M
    unsigned short* WB2  = WBIG + WPAD;
    unsigned short* R1   = (unsigned short*)(p + off); off += (size_t)M_*3*D_*2;  // 12.58M
    unsigned short* R2   = (unsigned short*)(p + off); off += (size_t)M_*D_*2;    // 4.19M
    unsigned short* R3   = (unsigned short*)(p + off); off += (size_t)M_*D_*2;    // 4.19M
    unsigned short* R4   = (unsigned short*)(p + off); off += (size_t)M_*D_*2;    // 4.19M

    unsigned short* h1    = R2;
    unsigned short* qkvb  = R1;
    unsigned short* attno = R2;   // after h1 dead
    unsigned short* xattn = R3;
    unsigned short* ybuf  = R4;
    unsigned short* h2b   = R2;   // after attno dead
    unsigned short* fbuf  = R1;   // after qkvb dead; [2048][DFFP]
    unsigned short* xffb  = R3;   // after xattn dead

    // 1. out = x  (fp32 pass-through; selected rows overwritten by scatter)
    k_copyf<<<2048, 256, 0, stream>>>((const float4*)x, (float4*)out, (B_*T_*D_) / 4);
    // 2. router scores
    k_router<<<(B_*T_) / 4, 256, 0, stream>>>(x, w_rt, scores);
    // 3. exact top-k
    k_topk<<<B_, 1024, 0, stream>>>(scores, idx);
    // 4. gather + rmsnorm(g1) -> h1 (bf16)
    k_gather_rms<<<M_, 256, 0, stream>>>(x, idx, g1, h1);
    // 5. qkv = h1 @ W_qkv^T   [2048 x 3072], K=1024
    k_f2b<<<2048, 256, 0, stream>>>((const float4*)W_qkv, (ushort4*)WBIG, (3*D_*D_) / 4);
    k_gemm64g<<<dim3(M_/64, 3*D_/128), 256, 0, stream>>>(h1, WBIG, qkvb, 3*D_, D_);
    // 6. MFMA flash attention
    k_attn_mfma<<<dim3(CAP_/64, H_, B_), 256, 0, stream>>>(qkvb, attno);
    // 7. x_attn = o @ W_out^T  [2048 x 1024], K=1024
    k_f2b<<<1024, 256, 0, stream>>>((const float4*)W_out, (ushort4*)WBIG, (D_*D_) / 4);
    k_gemm64g<<<dim3(M_/64, D_/128), 256, 0, stream>>>(attno, WBIG, xattn, D_, D_);
    // 8. y = x_sel + xattn; h2 = rmsnorm(y, g2)
    k_add_rms<<<M_, 256, 0, stream>>>(x, idx, xattn, g2, ybuf, h2b);
    // 9+10. f = silu(h2@W1^T) * (h2@W2^T)  — FUSED; pad cols exact zero
    k_f2b_rowpad<<<2048, 256, 0, stream>>>(W1, WBIG, D_/8, DFF_, DFFR*(D_/8));
    k_f2b_rowpad<<<2048, 256, 0, stream>>>(W2, WB2,  D_/8, DFF_, DFFR*(D_/8));
    k_gemm64g2<<<dim3(M_/64, DFFR/128), 256, 0, stream>>>(h2b, WBIG, WB2, fbuf,
                                                          DFFP, D_);
    // 11. x_ff = f @ W3^T   [2048 x 1024], K=DFFP (pad cols zero both sides)
    k_f2b_pad<<<2048, 256, 0, stream>>>(W3, WBIG, DFF_, DFFP, D_);
    k_gemm64g<<<dim3(M_/64, D_/128), 256, 0, stream>>>(fbuf, WBIG, xffb, D_, DFFP);
    // 12. out[b, idx, :] = y + x_ff  (fp32)
    k_scatter<<<M_, 256, 0, stream>>>(ybuf, xffb, idx, out);
}

// Round 16
// 252.757 us; speedup vs baseline: 1.4063x; 1.0434x over previous
//
#include <hip/hip_runtime.h>
#include <hip/hip_bf16.h>

// MoD transformer block: B=4, T=4096, D=1024, H=16, HD=64, CAP=512, DFF=2730
// Inputs fp32, output fp32. Round 16: k_topk rewritten — exact 8-bit radix
// select (registers + 256-bin LDS histogram, 4 rounds) + rank-scatter instead
// of 78-stage bitonic sort (was 57us, 0.7us/barrier-stage). Selection and
// ordering semantics identical (desc score, asc index ties). Rest = r15.

#define B_   4
#define T_   4096
#define D_   1024
#define H_   16
#define HD_  64
#define CAP_ 512
#define DFF_ 2730
#define DFFP 2752               // DFF padded to mult of 64 (K-path)
#define DFFR 2816               // DFF padded to mult of 128 (B-row tiles)
#define M_   (B_*CAP_)          // 2048 selected rows total

typedef __attribute__((ext_vector_type(8))) short          s16x8;
typedef __attribute__((ext_vector_type(8))) unsigned short u16x8;
typedef __attribute__((ext_vector_type(4))) float          f32x4;

__device__ __forceinline__ float bf2f(unsigned short u) {
    union { float f; unsigned int i; } v; v.i = ((unsigned int)u) << 16; return v.f;
}
__device__ __forceinline__ unsigned short f2bf(float f) {
    union { float f; unsigned int i; } v; v.f = f;
    unsigned int r = v.i + 0x7fffu + ((v.i >> 16) & 1u);   // RNE
    return (unsigned short)(r >> 16);
}

// async global->LDS, 16B per lane; LDS dest = wave-uniform base + lane*16
__device__ __forceinline__ void gload_lds16(const unsigned short* g, unsigned short* l) {
    __builtin_amdgcn_global_load_lds(
        (const __attribute__((address_space(1))) unsigned int*)g,
        (__attribute__((address_space(3))) unsigned int*)l, 16, 0, 0);
}

// ---------------- out = x pass-through (fp32 copy) ----------------
__global__ __launch_bounds__(256) void k_copyf(const float4* __restrict__ s,
                                               float4* __restrict__ d, int n4) {
    int i = blockIdx.x * 256 + threadIdx.x;
    int st = gridDim.x * 256;
    for (; i < n4; i += st) d[i] = s[i];
}

// ---------------- fp32 -> bf16 flat convert ----------------
__global__ __launch_bounds__(256) void k_f2b(const float4* __restrict__ s,
                                             ushort4* __restrict__ d, int n4) {
    int i = blockIdx.x * 256 + threadIdx.x;
    int st = gridDim.x * 256;
    for (; i < n4; i += st) {
        float4 v = s[i];
        ushort4 o;
        o.x = f2bf(v.x); o.y = f2bf(v.y); o.z = f2bf(v.z); o.w = f2bf(v.w);
        d[i] = o;
    }
}

// ---------------- fp32 [rows][K] -> bf16 [rowsP][K], pad ROWS zeroed ----------------
__global__ __launch_bounds__(256) void k_f2b_rowpad(const float* __restrict__ src,
                                                    unsigned short* __restrict__ dst,
                                                    int kc, int rows, int total) {
    int g = blockIdx.x * 256 + threadIdx.x;
    int st = gridDim.x * 256;
    for (; g < total; g += st) {
        int row = g / kc;
        u16x8 v = {0, 0, 0, 0, 0, 0, 0, 0};
        if (row < rows) {
            const float* s = src + ((size_t)g) * 8;
#pragma unroll
            for (int j = 0; j < 2; ++j) {
                float4 f = *(const float4*)(s + 4 * j);
                v[4*j]   = f2bf(f.x); v[4*j+1] = f2bf(f.y);
                v[4*j+2] = f2bf(f.z); v[4*j+3] = f2bf(f.w);
            }
        }
        *(u16x8*)(dst + (size_t)g * 8) = v;
    }
}

// ---------------- fp32 [rows][K] -> bf16 [rows][Kp], pad COLS zeroed ----------------
__global__ __launch_bounds__(256) void k_f2b_pad(const float* __restrict__ src,
                                                 unsigned short* __restrict__ dst,
                                                 int K, int Kp, int rows) {
    int g = blockIdx.x * 256 + threadIdx.x;
    int ng = rows * (Kp >> 3);
    int st = gridDim.x * 256;
    for (; g < ng; g += st) {
        int row = g / (Kp >> 3);
        int c = (g - row * (Kp >> 3)) << 3;
        const float* s = src + (size_t)row * K + c;
        u16x8 v;
        if (c + 8 <= K) {
#pragma unroll
            for (int j = 0; j < 4; ++j) {            // 8B-aligned (K,c even)
                float2 f = *(const float2*)(s + 2 * j);
                v[2*j] = f2bf(f.x); v[2*j+1] = f2bf(f.y);
            }
        } else {
#pragma unroll
            for (int j = 0; j < 8; ++j) v[j] = (c + j < K) ? f2bf(s[j]) : (unsigned short)0;
        }
        *(u16x8*)(dst + (size_t)row * Kp + c) = v;
    }
}

// ---------------- router scores: one wave per token row ----------------
__global__ __launch_bounds__(256) void k_router(const float* __restrict__ x,
                                                const float* __restrict__ wr,
                                                float* __restrict__ sc) {
    int gw   = (blockIdx.x * 256 + threadIdx.x) >> 6;   // 0..B*T-1
    int lane = threadIdx.x & 63;
    const float* row = x + (size_t)gw * D_;
    float s = 0.f;
#pragma unroll
    for (int p = 0; p < 4; ++p) {
        int c = p * 256 + lane * 4;
        float4 xv = *(const float4*)(row + c);
        float4 wv = *(const float4*)(wr + c);
        s += xv.x * wv.x + xv.y * wv.y + xv.z * wv.z + xv.w * wv.w;
    }
#pragma unroll
    for (int o = 32; o; o >>= 1) s += __shfl_xor(s, o);
    if (lane == 0) sc[gw] = s;
}

// ---------------- exact top-k via radix select + rank scatter ----------------
// keys: scorekey = ~sortable(score) (32b, smaller = better score);
// full key = scorekey<<32 | index (unique). Select 512 smallest full keys,
// output in ascending-key order == descending score, index-ascending ties.
// 4 rounds of 8-bit radix select on scorekey (registers), then compaction
// (LDS atomics) + tie resolution by smallest index + O(512^2) rank scatter.
__global__ __launch_bounds__(1024) void k_topk(const float* __restrict__ sc,
                                               int* __restrict__ idx) {
    __shared__ unsigned int hist[256];
    __shared__ unsigned long long okeys[CAP_];
    __shared__ unsigned int ecand[T_];      // eq-score candidate indices (worst case)
    __shared__ unsigned int sprefix;
    __shared__ int skneed;
    __shared__ unsigned int scnt, ecnt;
    int t = threadIdx.x;
    const float* s = sc + (size_t)blockIdx.x * T_;

    unsigned int sb[4], ei[4];
#pragma unroll
    for (int j = 0; j < 4; ++j) {
        int i = j * 1024 + t;
        union { float f; unsigned int u; } v; v.f = s[i];
        unsigned int k = (v.u & 0x80000000u) ? ~v.u : (v.u | 0x80000000u);
        sb[j] = ~k;             // smaller = better
        ei[j] = (unsigned int)i;
    }
    if (t == 0) { sprefix = 0; skneed = CAP_; scnt = 0; ecnt = 0; }

    // 4 radix rounds, 8 bits each, MSB first
#pragma unroll
    for (int rs = 24; rs >= 0; rs -= 8) {
        if (t < 256) hist[t] = 0;
        __syncthreads();
        unsigned int pfx = sprefix;
#pragma unroll
        for (int j = 0; j < 4; ++j) {
            if (((unsigned long long)(sb[j] ^ pfx) >> (rs + 8)) == 0ULL)
                atomicAdd(&hist[(sb[j] >> rs) & 255u], 1u);
        }
        __syncthreads();
        if (t == 0) {
            int need = skneed;
            unsigned int cum = 0;
            int b = 0;
            for (; b < 255; ++b) {
                unsigned int h = hist[b];
                if (cum + h >= (unsigned int)need) break;
                cum += h;
            }
            sprefix = pfx | ((unsigned int)b << rs);
            skneed = need - (int)cum;
        }
        __syncthreads();
    }

    unsigned int Sstar = sprefix;
    int neq = skneed;           // how many eq-score elements to admit (>=1)
    // compaction: strictly-better go straight in; eq-score become candidates
#pragma unroll
    for (int j = 0; j < 4; ++j) {
        if (sb[j] < Sstar) {
            unsigned int p = atomicAdd(&scnt, 1u);
            okeys[p] = ((unsigned long long)sb[j] << 32) | ei[j];
        } else if (sb[j] == Sstar) {
            unsigned int p = atomicAdd(&ecnt, 1u);
            ecand[p] = ei[j];
        }
    }
    __syncthreads();
    // admit the neq smallest indices among eq-score candidates
    if (t == 0) {
        unsigned int base = scnt;            // = 512 - neq
        unsigned int ne = ecnt;
        for (int q = 0; q < neq; ++q) {
            unsigned int mn = 0xffffffffu; int mi = 0;
            for (unsigned int e = 0; e < ne; ++e)
                if (ecand[e] < mn) { mn = ecand[e]; mi = (int)e; }
            okeys[base + q] = ((unsigned long long)Sstar << 32) | mn;
            ecand[mi] = 0xffffffffu;
        }
    }
    __syncthreads();
    // rank scatter: position = #(keys < mine); broadcast LDS reads, no barrier
    if (t < CAP_) {
        unsigned long long mine = okeys[t];
        int r = 0;
        for (int q = 0; q < CAP_; ++q) r += (okeys[q] < mine) ? 1 : 0;
        idx[blockIdx.x * CAP_ + r] = (int)(mine & 0xffffffffu);
    }
}

// ---------------- gather + RMSNorm(g1) -> h (bf16) ----------------
__global__ __launch_bounds__(256) void k_gather_rms(const float* __restrict__ x,
                                                    const int* __restrict__ idx,
                                                    const float* __restrict__ g,
                                                    unsigned short* __restrict__ h) {
    int r = blockIdx.x;                 // 0..M_-1
    int b = r >> 9;                     // /CAP_
    int src = idx[r] & (T_ - 1);
    const float* xr = x + ((size_t)b * T_ + src) * D_;
    int c = threadIdx.x * 4;
    float4 xv = *(const float4*)(xr + c);
    float ss = xv.x*xv.x + xv.y*xv.y + xv.z*xv.z + xv.w*xv.w;
#pragma unroll
    for (int o = 32; o; o >>= 1) ss += __shfl_xor(ss, o);
    __shared__ float red[4];
    int lane = threadIdx.x & 63, w = threadIdx.x >> 6;
    if (lane == 0) red[w] = ss;
    __syncthreads();
    float tot = red[0] + red[1] + red[2] + red[3];
    float scale = rsqrtf(tot * (1.f / D_) + 1e-6f);
    float4 gv = *(const float4*)(g + c);
    ushort4 hv;
    hv.x = f2bf(xv.x * scale * gv.x);
    hv.y = f2bf(xv.y * scale * gv.y);
    hv.z = f2bf(xv.z * scale * gv.z);
    hv.w = f2bf(xv.w * scale * gv.w);
    *(ushort4*)(h + (size_t)r * D_ + c) = hv;
}

// ---------------- MFMA GEMM 64x128 (BK=64), global_load_lds + XOR swizzle ----------------
__global__ __launch_bounds__(256) void k_gemm64g(const unsigned short* __restrict__ A,
                                                 const unsigned short* __restrict__ Bw,
                                                 unsigned short* __restrict__ C,
                                                 int Nout, int Kr) {
    __shared__ __align__(16) unsigned short As[64 * 64];    // linear, 8KB
    __shared__ __align__(16) unsigned short Bs[128 * 64];   // linear, 16KB
    int m0 = blockIdx.x * 64;
    int n0 = blockIdx.y * 128;
    int t = threadIdx.x;
    int w = t >> 6, lane = t & 63;
    int lr = lane & 15, lg = lane >> 4;
    int l8 = lane >> 3, lm8 = lane & 7;

    f32x4 acc[4][2];
#pragma unroll
    for (int mi = 0; mi < 4; ++mi)
#pragma unroll
        for (int ni = 0; ni < 2; ++ni) acc[mi][ni] = {0.f, 0.f, 0.f, 0.f};

    for (int k0 = 0; k0 < Kr; k0 += 64) {
#pragma unroll
        for (int j = 0; j < 2; ++j) {
            int r0 = w * 16 + j * 8;
            int row = r0 + l8;
            int cb = lm8 ^ (row & 7);
            gload_lds16(A + (size_t)(m0 + row) * Kr + k0 + cb * 8, &As[r0 * 64]);
        }
#pragma unroll
        for (int j = 0; j < 4; ++j) {
            int r0 = w * 32 + j * 8;
            int row = r0 + l8;
            int cb = lm8 ^ (row & 7);
            gload_lds16(Bw + (size_t)(n0 + row) * Kr + k0 + cb * 8, &Bs[r0 * 64]);
        }
        __syncthreads();
#pragma unroll
        for (int kh = 0; kh < 2; ++kh) {
            s16x8 af[4], bf[2];
#pragma unroll
            for (int i = 0; i < 4; ++i) {
                int row = i * 16 + lr;
                int pb = (kh * 4 + lg) ^ (row & 7);
                af[i] = *(const s16x8*)&As[row * 64 + pb * 8];
            }
#pragma unroll
            for (int i = 0; i < 2; ++i) {
                int row = w * 32 + i * 16 + lr;
                int pb = (kh * 4 + lg) ^ (row & 7);
                bf[i] = *(const s16x8*)&Bs[row * 64 + pb * 8];
            }
#pragma unroll
            for (int mi = 0; mi < 4; ++mi)
#pragma unroll
                for (int ni = 0; ni < 2; ++ni)
                    acc[mi][ni] = __builtin_amdgcn_mfma_f32_16x16x32_bf16(af[mi], bf[ni],
                                                                          acc[mi][ni], 0, 0, 0);
        }
        __syncthreads();
    }
    int orow0 = m0 + (lg << 2);
    int ocol0 = n0 + w * 32 + lr;
#pragma unroll
    for (int ni = 0; ni < 2; ++ni) {
        int col = ocol0 + ni * 16;
        if (col < Nout) {
#pragma unroll
            for (int mi = 0; mi < 4; ++mi)
#pragma unroll
                for (int i = 0; i < 4; ++i)
                    C[(size_t)(orow0 + mi * 16 + i) * Nout + col] = f2bf(acc[mi][ni][i]);
        }
    }
}

// ---------------- FUSED W1/W2 GEMM: F = silu(A*B1^T) * (A*B2^T) ----------------
__global__ __launch_bounds__(256) void k_gemm64g2(const unsigned short* __restrict__ A,
                                                  const unsigned short* __restrict__ B1,
                                                  const unsigned short* __restrict__ B2,
                                                  unsigned short* __restrict__ F,
                                                  int Nout, int Kr) {
    __shared__ __align__(16) unsigned short As[64 * 64];     // 8KB
    __shared__ __align__(16) unsigned short B1s[128 * 64];   // 16KB
    __shared__ __align__(16) unsigned short B2s[128 * 64];   // 16KB
    int m0 = blockIdx.x * 64;
    int n0 = blockIdx.y * 128;
    int t = threadIdx.x;
    int w = t >> 6, lane = t & 63;
    int lr = lane & 15, lg = lane >> 4;
    int l8 = lane >> 3, lm8 = lane & 7;

    f32x4 accU[4][2], accG[4][2];
#pragma unroll
    for (int mi = 0; mi < 4; ++mi)
#pragma unroll
        for (int ni = 0; ni < 2; ++ni) {
            accU[mi][ni] = {0.f, 0.f, 0.f, 0.f};
            accG[mi][ni] = {0.f, 0.f, 0.f, 0.f};
        }

    for (int k0 = 0; k0 < Kr; k0 += 64) {
#pragma unroll
        for (int j = 0; j < 2; ++j) {
            int r0 = w * 16 + j * 8;
            int row = r0 + l8;
            int cb = lm8 ^ (row & 7);
            gload_lds16(A + (size_t)(m0 + row) * Kr + k0 + cb * 8, &As[r0 * 64]);
        }
#pragma unroll
        for (int j = 0; j < 4; ++j) {
            int r0 = w * 32 + j * 8;
            int row = r0 + l8;
            int cb = lm8 ^ (row & 7);
            size_t goff = (size_t)(n0 + row) * Kr + k0 + cb * 8;
            gload_lds16(B1 + goff, &B1s[r0 * 64]);
            gload_lds16(B2 + goff, &B2s[r0 * 64]);
        }
        __syncthreads();
#pragma unroll
        for (int kh = 0; kh < 2; ++kh) {
            s16x8 af[4], b1f[2], b2f[2];
#pragma unroll
            for (int i = 0; i < 4; ++i) {
                int row = i * 16 + lr;
                int pb = (kh * 4 + lg) ^ (row & 7);
                af[i] = *(const s16x8*)&As[row * 64 + pb * 8];
            }
#pragma unroll
            for (int i = 0; i < 2; ++i) {
                int row = w * 32 + i * 16 + lr;
                int pb = (kh * 4 + lg) ^ (row & 7);
                b1f[i] = *(const s16x8*)&B1s[row * 64 + pb * 8];
                b2f[i] = *(const s16x8*)&B2s[row * 64 + pb * 8];
            }
#pragma unroll
            for (int mi = 0; mi < 4; ++mi)
#pragma unroll
                for (int ni = 0; ni < 2; ++ni) {
                    accU[mi][ni] = __builtin_amdgcn_mfma_f32_16x16x32_bf16(af[mi], b1f[ni],
                                                                           accU[mi][ni], 0, 0, 0);
                    accG[mi][ni] = __builtin_amdgcn_mfma_f32_16x16x32_bf16(af[mi], b2f[ni],
                                                                           accG[mi][ni], 0, 0, 0);
                }
        }
        __syncthreads();
    }
    int orow0 = m0 + (lg << 2);
    int ocol0 = n0 + w * 32 + lr;
#pragma unroll
    for (int ni = 0; ni < 2; ++ni) {
        int col = ocol0 + ni * 16;
        if (col < Nout) {
#pragma unroll
            for (int mi = 0; mi < 4; ++mi)
#pragma unroll
                for (int i = 0; i < 4; ++i) {
                    float u = accU[mi][ni][i];
                    float sl = u / (1.f + __expf(-u));
                    F[(size_t)(orow0 + mi * 16 + i) * Nout + col] = f2bf(sl * accG[mi][ni][i]);
                }
        }
    }
}

// ---------------- MFMA flash attention (causal, gathered order) ----------------
__global__ __launch_bounds__(256) void k_attn_mfma(const unsigned short* __restrict__ qkv,
                                                   unsigned short* __restrict__ o) {
    __shared__ __align__(16) unsigned short Ks[32][72];
    __shared__ __align__(16) unsigned short Vt[64][40];
    __shared__ __align__(16) unsigned short Ps[4][16][40];
    int qt = blockIdx.x, h = blockIdx.y, b = blockIdx.z;
    int q0 = qt * 64;
    int t = threadIdx.x, w = t >> 6, lane = t & 63;
    int lr = lane & 15, lg = lane >> 4;
    const unsigned short* base = qkv + (size_t)b * CAP_ * 3 * D_;

    int qrow = q0 + w * 16 + lr;
    const unsigned short* qp = base + (size_t)qrow * 3 * D_ + h * 64;
    s16x8 aq0 = *(const s16x8*)(qp + lg * 8);
    s16x8 aq1 = *(const s16x8*)(qp + 32 + lg * 8);

    f32x4 zero = {0.f, 0.f, 0.f, 0.f};
    f32x4 oacc[4] = {zero, zero, zero, zero};
    float m_[4], l_[4];
#pragma unroll
    for (int i = 0; i < 4; ++i) { m_[i] = -3.0e38f; l_[i] = 0.f; }

    int qbase = q0 + w * 16 + lg * 4;
    int ntile = (q0 + 64) >> 5;

    int skv = t >> 3, sc = (t & 7) * 8;
    for (int kt = 0; kt < ntile; ++kt) {
        int kv0 = kt << 5;
        {
            const unsigned short* kr = base + (size_t)(kv0 + skv) * 3 * D_ + D_     + h * 64 + sc;
            const unsigned short* vr = base + (size_t)(kv0 + skv) * 3 * D_ + 2 * D_ + h * 64 + sc;
            *(u16x8*)&Ks[skv][sc] = *(const u16x8*)kr;
            u16x8 vv = *(const u16x8*)vr;
#pragma unroll
            for (int j = 0; j < 8; ++j) Vt[sc + j][skv] = vv[j];
        }
        __syncthreads();
        f32x4 s0 = zero, s1 = zero;
        s16x8 k00 = *(const s16x8*)&Ks[lr][lg * 8];
        s16x8 k01 = *(const s16x8*)&Ks[lr][32 + lg * 8];
        s16x8 k10 = *(const s16x8*)&Ks[16 + lr][lg * 8];
        s16x8 k11 = *(const s16x8*)&Ks[16 + lr][32 + lg * 8];
        s0 = __builtin_amdgcn_mfma_f32_16x16x32_bf16(aq0, k00, s0, 0, 0, 0);
        s0 = __builtin_amdgcn_mfma_f32_16x16x32_bf16(aq1, k01, s0, 0, 0, 0);
        s1 = __builtin_amdgcn_mfma_f32_16x16x32_bf16(aq0, k10, s1, 0, 0, 0);
        s1 = __builtin_amdgcn_mfma_f32_16x16x32_bf16(aq1, k11, s1, 0, 0, 0);
#pragma unroll
        for (int i = 0; i < 4; ++i) {
            float v0 = s0[i] * 0.125f, v1 = s1[i] * 0.125f;
            if (kv0 + lr      > qbase + i) v0 = -3.0e38f;
            if (kv0 + 16 + lr > qbase + i) v1 = -3.0e38f;
            s0[i] = v0; s1[i] = v1;
        }
        float pm[4];
#pragma unroll
        for (int i = 0; i < 4; ++i) pm[i] = fmaxf(s0[i], s1[i]);
#pragma unroll
        for (int d = 1; d < 16; d <<= 1) {
#pragma unroll
            for (int i = 0; i < 4; ++i) pm[i] = fmaxf(pm[i], __shfl_xor(pm[i], d));
        }
        float p0[4], p1[4], ps[4], scl[4];
#pragma unroll
        for (int i = 0; i < 4; ++i) {
            float mn = fmaxf(m_[i], pm[i]);
            scl[i] = __expf(m_[i] - mn);
            p0[i] = __expf(s0[i] - mn);
            p1[i] = __expf(s1[i] - mn);
            ps[i] = p0[i] + p1[i];
            m_[i] = mn;
        }
#pragma unroll
        for (int d = 1; d < 16; d <<= 1) {
#pragma unroll
            for (int i = 0; i < 4; ++i) ps[i] += __shfl_xor(ps[i], d);
        }
#pragma unroll
        for (int i = 0; i < 4; ++i) l_[i] = l_[i] * scl[i] + ps[i];
#pragma unroll
        for (int dg = 0; dg < 4; ++dg)
#pragma unroll
            for (int i = 0; i < 4; ++i) oacc[dg][i] *= scl[i];
#pragma unroll
        for (int i = 0; i < 4; ++i) {
            Ps[w][lg * 4 + i][lr]      = f2bf(p0[i]);
            Ps[w][lg * 4 + i][16 + lr] = f2bf(p1[i]);
        }
        __syncthreads();
        s16x8 pa = *(const s16x8*)&Ps[w][lr][lg * 8];
#pragma unroll
        for (int dg = 0; dg < 4; ++dg) {
            s16x8 vf = *(const s16x8*)&Vt[dg * 16 + lr][lg * 8];
            oacc[dg] = __builtin_amdgcn_mfma_f32_16x16x32_bf16(pa, vf, oacc[dg], 0, 0, 0);
        }
        __syncthreads();
    }
    unsigned short* orow = o + ((size_t)(b * CAP_ + qbase)) * D_ + h * 64;
#pragma unroll
    for (int i = 0; i < 4; ++i) {
        float inv = 1.f / l_[i];
#pragma unroll
        for (int dg = 0; dg < 4; ++dg)
            orow[(size_t)i * D_ + dg * 16 + lr] = f2bf(oacc[dg][i] * inv);
    }
}

// ---------------- y = x_sel + xattn; h2 = rmsnorm(y, g2) ----------------
__global__ __launch_bounds__(256) void k_add_rms(const float* __restrict__ x,
                                                 const int* __restrict__ idx,
                                                 const unsigned short* __restrict__ xattn,
                                                 const float* __restrict__ g,
                                                 unsigned short* __restrict__ y,
                                                 unsigned short* __restrict__ h) {
    int r = blockIdx.x;
    int b = r >> 9;
    int src = idx[r] & (T_ - 1);
    int c = threadIdx.x * 4;
    const float* xr = x + ((size_t)b * T_ + src) * D_;
    float4 xv = *(const float4*)(xr + c);
    size_t off = (size_t)r * D_ + c;
    ushort4 a4 = *(const ushort4*)(xattn + off);
    float v0 = xv.x + bf2f(a4.x);
    float v1 = xv.y + bf2f(a4.y);
    float v2 = xv.z + bf2f(a4.z);
    float v3 = xv.w + bf2f(a4.w);
    float ss = v0*v0 + v1*v1 + v2*v2 + v3*v3;
#pragma unroll
    for (int o = 32; o; o >>= 1) ss += __shfl_xor(ss, o);
    __shared__ float red[4];
    int lane = threadIdx.x & 63, w = threadIdx.x >> 6;
    if (lane == 0) red[w] = ss;
    __syncthreads();
    float tot = red[0] + red[1] + red[2] + red[3];
    float scale = rsqrtf(tot * (1.f / D_) + 1e-6f);
    ushort4 yv;
    yv.x = f2bf(v0); yv.y = f2bf(v1); yv.z = f2bf(v2); yv.w = f2bf(v3);
    *(ushort4*)(y + off) = yv;
    float4 gv = *(const float4*)(g + c);
    ushort4 hv;
    hv.x = f2bf(v0 * scale * gv.x);
    hv.y = f2bf(v1 * scale * gv.y);
    hv.z = f2bf(v2 * scale * gv.z);
    hv.w = f2bf(v3 * scale * gv.w);
    *(ushort4*)(h + off) = hv;
}

// ---------------- scatter: out[b, idx, :] = y + xff  (fp32 out) ----------------
__global__ __launch_bounds__(256) void k_scatter(const unsigned short* __restrict__ y,
                                                 const unsigned short* __restrict__ xff,
                                                 const int* __restrict__ idx,
                                                 float* __restrict__ out) {
    int r = blockIdx.x;
    int b = r >> 9;
    int dst = idx[r] & (T_ - 1);
    int c = threadIdx.x * 4;
    size_t src = (size_t)r * D_ + c;
    ushort4 a4 = *(const ushort4*)(y + src);
    ushort4 f4 = *(const ushort4*)(xff + src);
    float4 o4;
    o4.x = bf2f(a4.x) + bf2f(f4.x);
    o4.y = bf2f(a4.y) + bf2f(f4.y);
    o4.z = bf2f(a4.z) + bf2f(f4.z);
    o4.w = bf2f(a4.w) + bf2f(f4.w);
    *(float4*)(out + ((size_t)b * T_ + dst) * D_ + c) = o4;
}

extern "C" void kernel_launch(void* const* d_in, const int* in_sizes, int n_in,
                              void* d_out, int out_size, void* d_ws, size_t ws_size,
                              hipStream_t stream) {
    const float* x     = (const float*)d_in[0];
    const float* w_rt  = (const float*)d_in[1];
    const float* W_qkv = (const float*)d_in[2];
    const float* W_out = (const float*)d_in[3];
    const float* g1    = (const float*)d_in[4];
    const float* g2    = (const float*)d_in[5];
    const float* W1    = (const float*)d_in[6];
    const float* W2    = (const float*)d_in[7];
    const float* W3    = (const float*)d_in[8];
    float* out = (float*)d_out;

    // ---- workspace: ~37 MiB (identical to r15) ----
    char* p = (char*)d_ws;
    float* scores = (float*)p;
    int*   idx    = (int*)(p + 65536);
    size_t off = 131072;
    const size_t WPAD = (size_t)DFFR * D_;
    unsigned short* WBIG = (unsigned short*)(p + off); off += 2 * WPAD * 2;
    unsigned short* WB2  = WBIG + WPAD;
    unsigned short* R1   = (unsigned short*)(p + off); off += (size_t)M_*3*D_*2;
    unsigned short* R2   = (unsigned short*)(p + off); off += (size_t)M_*D_*2;
    unsigned short* R3   = (unsigned short*)(p + off); off += (size_t)M_*D_*2;
    unsigned short* R4   = (unsigned short*)(p + off); off += (size_t)M_*D_*2;

    unsigned short* h1    = R2;
    unsigned short* qkvb  = R1;
    unsigned short* attno = R2;   // after h1 dead
    unsigned short* xattn = R3;
    unsigned short* ybuf  = R4;
    unsigned short* h2b   = R2;   // after attno dead
    unsigned short* fbuf  = R1;   // after qkvb dead; [2048][DFFP]
    unsigned short* xffb  = R3;   // after xattn dead

    // 1. out = x
    k_copyf<<<2048, 256, 0, stream>>>((const float4*)x, (float4*)out, (B_*T_*D_) / 4);
    // 2. router scores
    k_router<<<(B_*T_) / 4, 256, 0, stream>>>(x, w_rt, scores);
    // 3. exact top-k (radix select + rank scatter)
    k_topk<<<B_, 1024, 0, stream>>>(scores, idx);
    // 4. gather + rmsnorm(g1) -> h1 (bf16)
    k_gather_rms<<<M_, 256, 0, stream>>>(x, idx, g1, h1);
    // 5. qkv = h1 @ W_qkv^T   [2048 x 3072], K=1024
    k_f2b<<<2048, 256, 0, stream>>>((const float4*)W_qkv, (ushort4*)WBIG, (3*D_*D_) / 4);
    k_gemm64g<<<dim3(M_/64, 3*D_/128), 256, 0, stream>>>(h1, WBIG, qkvb, 3*D_, D_);
    // 6. MFMA flash attention
    k_attn_mfma<<<dim3(CAP_/64, H_, B_), 256, 0, stream>>>(qkvb, attno);
    // 7. x_attn = o @ W_out^T  [2048 x 1024], K=1024
    k_f2b<<<1024, 256, 0, stream>>>((const float4*)W_out, (ushort4*)WBIG, (D_*D_) / 4);
    k_gemm64g<<<dim3(M_/64, D_/128), 256, 0, stream>>>(attno, WBIG, xattn, D_, D_);
    // 8. y = x_sel + xattn; h2 = rmsnorm(y, g2)
    k_add_rms<<<M_, 256, 0, stream>>>(x, idx, xattn, g2, ybuf, h2b);
    // 9+10. f = silu(h2@W1^T) * (h2@W2^T)  — FUSED
    k_f2b_rowpad<<<2048, 256, 0, stream>>>(W1, WBIG, D_/8, DFF_, DFFR*(D_/8));
    k_f2b_rowpad<<<2048, 256, 0, stream>>>(W2, WB2,  D_/8, DFF_, DFFR*(D_/8));
    k_gemm64g2<<<dim3(M_/64, DFFR/128), 256, 0, stream>>>(h2b, WBIG, WB2, fbuf,
                                                          DFFP, D_);
    // 11. x_ff = f @ W3^T   [2048 x 1024], K=DFFP
    k_f2b_pad<<<2048, 256, 0, stream>>>(W3, WBIG, DFF_, DFFP, D_);
    k_gemm64g<<<dim3(M_/64, D_/128), 256, 0, stream>>>(fbuf, WBIG, xffb, D_, DFFP);
    // 12. out[b, idx, :] = y + x_ff  (fp32)
    k_scatter<<<M_, 256, 0, stream>>>(ybuf, xffb, idx, out);
}

// Round 17
// 222.637 us; speedup vs baseline: 1.5965x; 1.1353x over previous
//
#include <hip/hip_runtime.h>
#include <hip/hip_bf16.h>

// MoD transformer block: B=4, T=4096, D=1024, H=16, HD=64, CAP=512, DFF=2730
// Inputs fp32, output fp32. Round 17: k_topk histogram scan parallelized —
// r16's thread-0 256-bin serial scan (data-dependent break -> ~10us/round
// dependent-LDS chain, 4 rounds = the whole 45us) replaced by a wave-0
// shfl_up exclusive scan (64 lanes x 4 bins, no barriers). Rest = r16.

#define B_   4
#define T_   4096
#define D_   1024
#define H_   16
#define HD_  64
#define CAP_ 512
#define DFF_ 2730
#define DFFP 2752               // DFF padded to mult of 64 (K-path)
#define DFFR 2816               // DFF padded to mult of 128 (B-row tiles)
#define M_   (B_*CAP_)          // 2048 selected rows total

typedef __attribute__((ext_vector_type(8))) short          s16x8;
typedef __attribute__((ext_vector_type(8))) unsigned short u16x8;
typedef __attribute__((ext_vector_type(4))) float          f32x4;

__device__ __forceinline__ float bf2f(unsigned short u) {
    union { float f; unsigned int i; } v; v.i = ((unsigned int)u) << 16; return v.f;
}
__device__ __forceinline__ unsigned short f2bf(float f) {
    union { float f; unsigned int i; } v; v.f = f;
    unsigned int r = v.i + 0x7fffu + ((v.i >> 16) & 1u);   // RNE
    return (unsigned short)(r >> 16);
}

// async global->LDS, 16B per lane; LDS dest = wave-uniform base + lane*16
__device__ __forceinline__ void gload_lds16(const unsigned short* g, unsigned short* l) {
    __builtin_amdgcn_global_load_lds(
        (const __attribute__((address_space(1))) unsigned int*)g,
        (__attribute__((address_space(3))) unsigned int*)l, 16, 0, 0);
}

// ---------------- out = x pass-through (fp32 copy) ----------------
__global__ __launch_bounds__(256) void k_copyf(const float4* __restrict__ s,
                                               float4* __restrict__ d, int n4) {
    int i = blockIdx.x * 256 + threadIdx.x;
    int st = gridDim.x * 256;
    for (; i < n4; i += st) d[i] = s[i];
}

// ---------------- fp32 -> bf16 flat convert ----------------
__global__ __launch_bounds__(256) void k_f2b(const float4* __restrict__ s,
                                             ushort4* __restrict__ d, int n4) {
    int i = blockIdx.x * 256 + threadIdx.x;
    int st = gridDim.x * 256;
    for (; i < n4; i += st) {
        float4 v = s[i];
        ushort4 o;
        o.x = f2bf(v.x); o.y = f2bf(v.y); o.z = f2bf(v.z); o.w = f2bf(v.w);
        d[i] = o;
    }
}

// ---------------- fp32 [rows][K] -> bf16 [rowsP][K], pad ROWS zeroed ----------------
__global__ __launch_bounds__(256) void k_f2b_rowpad(const float* __restrict__ src,
                                                    unsigned short* __restrict__ dst,
                                                    int kc, int rows, int total) {
    int g = blockIdx.x * 256 + threadIdx.x;
    int st = gridDim.x * 256;
    for (; g < total; g += st) {
        int row = g / kc;
        u16x8 v = {0, 0, 0, 0, 0, 0, 0, 0};
        if (row < rows) {
            const float* s = src + ((size_t)g) * 8;
#pragma unroll
            for (int j = 0; j < 2; ++j) {
                float4 f = *(const float4*)(s + 4 * j);
                v[4*j]   = f2bf(f.x); v[4*j+1] = f2bf(f.y);
                v[4*j+2] = f2bf(f.z); v[4*j+3] = f2bf(f.w);
            }
        }
        *(u16x8*)(dst + (size_t)g * 8) = v;
    }
}

// ---------------- fp32 [rows][K] -> bf16 [rows][Kp], pad COLS zeroed ----------------
__global__ __launch_bounds__(256) void k_f2b_pad(const float* __restrict__ src,
                                                 unsigned short* __restrict__ dst,
                                                 int K, int Kp, int rows) {
    int g = blockIdx.x * 256 + threadIdx.x;
    int ng = rows * (Kp >> 3);
    int st = gridDim.x * 256;
    for (; g < ng; g += st) {
        int row = g / (Kp >> 3);
        int c = (g - row * (Kp >> 3)) << 3;
        const float* s = src + (size_t)row * K + c;
        u16x8 v;
        if (c + 8 <= K) {
#pragma unroll
            for (int j = 0; j < 4; ++j) {            // 8B-aligned (K,c even)
                float2 f = *(const float2*)(s + 2 * j);
                v[2*j] = f2bf(f.x); v[2*j+1] = f2bf(f.y);
            }
        } else {
#pragma unroll
            for (int j = 0; j < 8; ++j) v[j] = (c + j < K) ? f2bf(s[j]) : (unsigned short)0;
        }
        *(u16x8*)(dst + (size_t)row * Kp + c) = v;
    }
}

// ---------------- router scores: one wave per token row ----------------
__global__ __launch_bounds__(256) void k_router(const float* __restrict__ x,
                                                const float* __restrict__ wr,
                                                float* __restrict__ sc) {
    int gw   = (blockIdx.x * 256 + threadIdx.x) >> 6;   // 0..B*T-1
    int lane = threadIdx.x & 63;
    const float* row = x + (size_t)gw * D_;
    float s = 0.f;
#pragma unroll
    for (int p = 0; p < 4; ++p) {
        int c = p * 256 + lane * 4;
        float4 xv = *(const float4*)(row + c);
        float4 wv = *(const float4*)(wr + c);
        s += xv.x * wv.x + xv.y * wv.y + xv.z * wv.z + xv.w * wv.w;
    }
#pragma unroll
    for (int o = 32; o; o >>= 1) s += __shfl_xor(s, o);
    if (lane == 0) sc[gw] = s;
}

// ---------------- exact top-k via radix select + rank scatter ----------------
// 4 rounds of 8-bit radix select; histogram scan done by wave 0 in parallel
// (64 lanes x 4 bins, shfl_up exclusive scan). Compaction + smallest-index
// tie resolution + O(512^2) rank scatter reproduce jax.lax.top_k order.
__global__ __launch_bounds__(1024) void k_topk(const float* __restrict__ sc,
                                               int* __restrict__ idx) {
    __shared__ unsigned int hist[256];
    __shared__ unsigned long long okeys[CAP_];
    __shared__ unsigned int ecand[T_];      // eq-score candidates (worst case)
    __shared__ unsigned int sprefix;
    __shared__ int skneed;
    __shared__ unsigned int scnt, ecnt;
    int t = threadIdx.x;
    const float* s = sc + (size_t)blockIdx.x * T_;

    unsigned int sb[4], ei[4];
#pragma unroll
    for (int j = 0; j < 4; ++j) {
        int i = j * 1024 + t;
        union { float f; unsigned int u; } v; v.f = s[i];
        unsigned int k = (v.u & 0x80000000u) ? ~v.u : (v.u | 0x80000000u);
        sb[j] = ~k;             // smaller = better
        ei[j] = (unsigned int)i;
    }
    if (t == 0) { sprefix = 0; skneed = CAP_; scnt = 0; ecnt = 0; }

    // 4 radix rounds, 8 bits each, MSB first
#pragma unroll
    for (int rs = 24; rs >= 0; rs -= 8) {
        if (t < 256) hist[t] = 0;
        __syncthreads();
        unsigned int pfx = sprefix;
#pragma unroll
        for (int j = 0; j < 4; ++j) {
            if (((unsigned long long)(sb[j] ^ pfx) >> (rs + 8)) == 0ULL)
                atomicAdd(&hist[(sb[j] >> rs) & 255u], 1u);
        }
        __syncthreads();
        // wave-0 parallel scan: lane owns bins 4t..4t+3
        if (t < 64) {
            unsigned int h0 = hist[t * 4], h1 = hist[t * 4 + 1];
            unsigned int h2 = hist[t * 4 + 2], h3 = hist[t * 4 + 3];
            unsigned int lsum = h0 + h1 + h2 + h3;
            unsigned int run = lsum;
#pragma unroll
            for (int d = 1; d < 64; d <<= 1) {
                unsigned int v = __shfl_up(run, d);
                if (t >= d) run += v;
            }
            unsigned int excl = run - lsum;      // exclusive prefix of lane group
            int need = skneed;
            if (excl < (unsigned int)need && run >= (unsigned int)need) {
                unsigned int cum = excl;
                int b = t * 4;
                if (cum + h0 < (unsigned int)need) { cum += h0; ++b;
                    if (cum + h1 < (unsigned int)need) { cum += h1; ++b;
                        if (cum + h2 < (unsigned int)need) { cum += h2; ++b; } } }
                sprefix = pfx | ((unsigned int)b << rs);
                skneed = need - (int)cum;
            }
        }
        __syncthreads();
    }

    unsigned int Sstar = sprefix;
    int neq = skneed;           // eq-score elements to admit (>=1)
#pragma unroll
    for (int j = 0; j < 4; ++j) {
        if (sb[j] < Sstar) {
            unsigned int p = atomicAdd(&scnt, 1u);
            okeys[p] = ((unsigned long long)sb[j] << 32) | ei[j];
        } else if (sb[j] == Sstar) {
            unsigned int p = atomicAdd(&ecnt, 1u);
            ecand[p] = ei[j];
        }
    }
    __syncthreads();
    if (t == 0) {
        unsigned int base = scnt;            // = 512 - neq
        unsigned int ne = ecnt;
        for (int q = 0; q < neq; ++q) {
            unsigned int mn = 0xffffffffu; int mi = 0;
            for (unsigned int e = 0; e < ne; ++e)
                if (ecand[e] < mn) { mn = ecand[e]; mi = (int)e; }
            okeys[base + q] = ((unsigned long long)Sstar << 32) | mn;
            ecand[mi] = 0xffffffffu;
        }
    }
    __syncthreads();
    // rank scatter: position = #(keys < mine)
    if (t < CAP_) {
        unsigned long long mine = okeys[t];
        int r = 0;
#pragma unroll 8
        for (int q = 0; q < CAP_; ++q) r += (okeys[q] < mine) ? 1 : 0;
        idx[blockIdx.x * CAP_ + r] = (int)(mine & 0xffffffffu);
    }
}

// ---------------- gather + RMSNorm(g1) -> h (bf16) ----------------
__global__ __launch_bounds__(256) void k_gather_rms(const float* __restrict__ x,
                                                    const int* __restrict__ idx,
                                                    const float* __restrict__ g,
                                                    unsigned short* __restrict__ h) {
    int r = blockIdx.x;                 // 0..M_-1
    int b = r >> 9;                     // /CAP_
    int src = idx[r] & (T_ - 1);
    const float* xr = x + ((size_t)b * T_ + src) * D_;
    int c = threadIdx.x * 4;
    float4 xv = *(const float4*)(xr + c);
    float ss = xv.x*xv.x + xv.y*xv.y + xv.z*xv.z + xv.w*xv.w;
#pragma unroll
    for (int o = 32; o; o >>= 1) ss += __shfl_xor(ss, o);
    __shared__ float red[4];
    int lane = threadIdx.x & 63, w = threadIdx.x >> 6;
    if (lane == 0) red[w] = ss;
    __syncthreads();
    float tot = red[0] + red[1] + red[2] + red[3];
    float scale = rsqrtf(tot * (1.f / D_) + 1e-6f);
    float4 gv = *(const float4*)(g + c);
    ushort4 hv;
    hv.x = f2bf(xv.x * scale * gv.x);
    hv.y = f2bf(xv.y * scale * gv.y);
    hv.z = f2bf(xv.z * scale * gv.z);
    hv.w = f2bf(xv.w * scale * gv.w);
    *(ushort4*)(h + (size_t)r * D_ + c) = hv;
}

// ---------------- MFMA GEMM 64x128 (BK=64), global_load_lds + XOR swizzle ----------------
__global__ __launch_bounds__(256) void k_gemm64g(const unsigned short* __restrict__ A,
                                                 const unsigned short* __restrict__ Bw,
                                                 unsigned short* __restrict__ C,
                                                 int Nout, int Kr) {
    __shared__ __align__(16) unsigned short As[64 * 64];    // linear, 8KB
    __shared__ __align__(16) unsigned short Bs[128 * 64];   // linear, 16KB
    int m0 = blockIdx.x * 64;
    int n0 = blockIdx.y * 128;
    int t = threadIdx.x;
    int w = t >> 6, lane = t & 63;
    int lr = lane & 15, lg = lane >> 4;
    int l8 = lane >> 3, lm8 = lane & 7;

    f32x4 acc[4][2];
#pragma unroll
    for (int mi = 0; mi < 4; ++mi)
#pragma unroll
        for (int ni = 0; ni < 2; ++ni) acc[mi][ni] = {0.f, 0.f, 0.f, 0.f};

    for (int k0 = 0; k0 < Kr; k0 += 64) {
#pragma unroll
        for (int j = 0; j < 2; ++j) {
            int r0 = w * 16 + j * 8;
            int row = r0 + l8;
            int cb = lm8 ^ (row & 7);
            gload_lds16(A + (size_t)(m0 + row) * Kr + k0 + cb * 8, &As[r0 * 64]);
        }
#pragma unroll
        for (int j = 0; j < 4; ++j) {
            int r0 = w * 32 + j * 8;
            int row = r0 + l8;
            int cb = lm8 ^ (row & 7);
            gload_lds16(Bw + (size_t)(n0 + row) * Kr + k0 + cb * 8, &Bs[r0 * 64]);
        }
        __syncthreads();
#pragma unroll
        for (int kh = 0; kh < 2; ++kh) {
            s16x8 af[4], bf[2];
#pragma unroll
            for (int i = 0; i < 4; ++i) {
                int row = i * 16 + lr;
                int pb = (kh * 4 + lg) ^ (row & 7);
                af[i] = *(const s16x8*)&As[row * 64 + pb * 8];
            }
#pragma unroll
            for (int i = 0; i < 2; ++i) {
                int row = w * 32 + i * 16 + lr;
                int pb = (kh * 4 + lg) ^ (row & 7);
                bf[i] = *(const s16x8*)&Bs[row * 64 + pb * 8];
            }
#pragma unroll
            for (int mi = 0; mi < 4; ++mi)
#pragma unroll
                for (int ni = 0; ni < 2; ++ni)
                    acc[mi][ni] = __builtin_amdgcn_mfma_f32_16x16x32_bf16(af[mi], bf[ni],
                                                                          acc[mi][ni], 0, 0, 0);
        }
        __syncthreads();
    }
    int orow0 = m0 + (lg << 2);
    int ocol0 = n0 + w * 32 + lr;
#pragma unroll
    for (int ni = 0; ni < 2; ++ni) {
        int col = ocol0 + ni * 16;
        if (col < Nout) {
#pragma unroll
            for (int mi = 0; mi < 4; ++mi)
#pragma unroll
                for (int i = 0; i < 4; ++i)
                    C[(size_t)(orow0 + mi * 16 + i) * Nout + col] = f2bf(acc[mi][ni][i]);
        }
    }
}

// ---------------- FUSED W1/W2 GEMM: F = silu(A*B1^T) * (A*B2^T) ----------------
__global__ __launch_bounds__(256) void k_gemm64g2(const unsigned short* __restrict__ A,
                                                  const unsigned short* __restrict__ B1,
                                                  const unsigned short* __restrict__ B2,
                                                  unsigned short* __restrict__ F,
                                                  int Nout, int Kr) {
    __shared__ __align__(16) unsigned short As[64 * 64];     // 8KB
    __shared__ __align__(16) unsigned short B1s[128 * 64];   // 16KB
    __shared__ __align__(16) unsigned short B2s[128 * 64];   // 16KB
    int m0 = blockIdx.x * 64;
    int n0 = blockIdx.y * 128;
    int t = threadIdx.x;
    int w = t >> 6, lane = t & 63;
    int lr = lane & 15, lg = lane >> 4;
    int l8 = lane >> 3, lm8 = lane & 7;

    f32x4 accU[4][2], accG[4][2];
#pragma unroll
    for (int mi = 0; mi < 4; ++mi)
#pragma unroll
        for (int ni = 0; ni < 2; ++ni) {
            accU[mi][ni] = {0.f, 0.f, 0.f, 0.f};
            accG[mi][ni] = {0.f, 0.f, 0.f, 0.f};
        }

    for (int k0 = 0; k0 < Kr; k0 += 64) {
#pragma unroll
        for (int j = 0; j < 2; ++j) {
            int r0 = w * 16 + j * 8;
            int row = r0 + l8;
            int cb = lm8 ^ (row & 7);
            gload_lds16(A + (size_t)(m0 + row) * Kr + k0 + cb * 8, &As[r0 * 64]);
        }
#pragma unroll
        for (int j = 0; j < 4; ++j) {
            int r0 = w * 32 + j * 8;
            int row = r0 + l8;
            int cb = lm8 ^ (row & 7);
            size_t goff = (size_t)(n0 + row) * Kr + k0 + cb * 8;
            gload_lds16(B1 + goff, &B1s[r0 * 64]);
            gload_lds16(B2 + goff, &B2s[r0 * 64]);
        }
        __syncthreads();
#pragma unroll
        for (int kh = 0; kh < 2; ++kh) {
            s16x8 af[4], b1f[2], b2f[2];
#pragma unroll
            for (int i = 0; i < 4; ++i) {
                int row = i * 16 + lr;
                int pb = (kh * 4 + lg) ^ (row & 7);
                af[i] = *(const s16x8*)&As[row * 64 + pb * 8];
            }
#pragma unroll
            for (int i = 0; i < 2; ++i) {
                int row = w * 32 + i * 16 + lr;
                int pb = (kh * 4 + lg) ^ (row & 7);
                b1f[i] = *(const s16x8*)&B1s[row * 64 + pb * 8];
                b2f[i] = *(const s16x8*)&B2s[row * 64 + pb * 8];
            }
#pragma unroll
            for (int mi = 0; mi < 4; ++mi)
#pragma unroll
                for (int ni = 0; ni < 2; ++ni) {
                    accU[mi][ni] = __builtin_amdgcn_mfma_f32_16x16x32_bf16(af[mi], b1f[ni],
                                                                           accU[mi][ni], 0, 0, 0);
                    accG[mi][ni] = __builtin_amdgcn_mfma_f32_16x16x32_bf16(af[mi], b2f[ni],
                                                                           accG[mi][ni], 0, 0, 0);
                }
        }
        __syncthreads();
    }
    int orow0 = m0 + (lg << 2);
    int ocol0 = n0 + w * 32 + lr;
#pragma unroll
    for (int ni = 0; ni < 2; ++ni) {
        int col = ocol0 + ni * 16;
        if (col < Nout) {
#pragma unroll
            for (int mi = 0; mi < 4; ++mi)
#pragma unroll
                for (int i = 0; i < 4; ++i) {
                    float u = accU[mi][ni][i];
                    float sl = u / (1.f + __expf(-u));
                    F[(size_t)(orow0 + mi * 16 + i) * Nout + col] = f2bf(sl * accG[mi][ni][i]);
                }
        }
    }
}

// ---------------- MFMA flash attention (causal, gathered order) ----------------
__global__ __launch_bounds__(256) void k_attn_mfma(const unsigned short* __restrict__ qkv,
                                                   unsigned short* __restrict__ o) {
    __shared__ __align__(16) unsigned short Ks[32][72];
    __shared__ __align__(16) unsigned short Vt[64][40];
    __shared__ __align__(16) unsigned short Ps[4][16][40];
    int qt = blockIdx.x, h = blockIdx.y, b = blockIdx.z;
    int q0 = qt * 64;
    int t = threadIdx.x, w = t >> 6, lane = t & 63;
    int lr = lane & 15, lg = lane >> 4;
    const unsigned short* base = qkv + (size_t)b * CAP_ * 3 * D_;

    int qrow = q0 + w * 16 + lr;
    const unsigned short* qp = base + (size_t)qrow * 3 * D_ + h * 64;
    s16x8 aq0 = *(const s16x8*)(qp + lg * 8);
    s16x8 aq1 = *(const s16x8*)(qp + 32 + lg * 8);

    f32x4 zero = {0.f, 0.f, 0.f, 0.f};
    f32x4 oacc[4] = {zero, zero, zero, zero};
    float m_[4], l_[4];
#pragma unroll
    for (int i = 0; i < 4; ++i) { m_[i] = -3.0e38f; l_[i] = 0.f; }

    int qbase = q0 + w * 16 + lg * 4;
    int ntile = (q0 + 64) >> 5;

    int skv = t >> 3, sc = (t & 7) * 8;
    for (int kt = 0; kt < ntile; ++kt) {
        int kv0 = kt << 5;
        {
            const unsigned short* kr = base + (size_t)(kv0 + skv) * 3 * D_ + D_     + h * 64 + sc;
            const unsigned short* vr = base + (size_t)(kv0 + skv) * 3 * D_ + 2 * D_ + h * 64 + sc;
            *(u16x8*)&Ks[skv][sc] = *(const u16x8*)kr;
            u16x8 vv = *(const u16x8*)vr;
#pragma unroll
            for (int j = 0; j < 8; ++j) Vt[sc + j][skv] = vv[j];
        }
        __syncthreads();
        f32x4 s0 = zero, s1 = zero;
        s16x8 k00 = *(const s16x8*)&Ks[lr][lg * 8];
        s16x8 k01 = *(const s16x8*)&Ks[lr][32 + lg * 8];
        s16x8 k10 = *(const s16x8*)&Ks[16 + lr][lg * 8];
        s16x8 k11 = *(const s16x8*)&Ks[16 + lr][32 + lg * 8];
        s0 = __builtin_amdgcn_mfma_f32_16x16x32_bf16(aq0, k00, s0, 0, 0, 0);
        s0 = __builtin_amdgcn_mfma_f32_16x16x32_bf16(aq1, k01, s0, 0, 0, 0);
        s1 = __builtin_amdgcn_mfma_f32_16x16x32_bf16(aq0, k10, s1, 0, 0, 0);
        s1 = __builtin_amdgcn_mfma_f32_16x16x32_bf16(aq1, k11, s1, 0, 0, 0);
#pragma unroll
        for (int i = 0; i < 4; ++i) {
            float v0 = s0[i] * 0.125f, v1 = s1[i] * 0.125f;
            if (kv0 + lr      > qbase + i) v0 = -3.0e38f;
            if (kv0 + 16 + lr > qbase + i) v1 = -3.0e38f;
            s0[i] = v0; s1[i] = v1;
        }
        float pm[4];
#pragma unroll
        for (int i = 0; i < 4; ++i) pm[i] = fmaxf(s0[i], s1[i]);
#pragma unroll
        for (int d = 1; d < 16; d <<= 1) {
#pragma unroll
            for (int i = 0; i < 4; ++i) pm[i] = fmaxf(pm[i], __shfl_xor(pm[i], d));
        }
        float p0[4], p1[4], ps[4], scl[4];
#pragma unroll
        for (int i = 0; i < 4; ++i) {
            float mn = fmaxf(m_[i], pm[i]);
            scl[i] = __expf(m_[i] - mn);
            p0[i] = __expf(s0[i] - mn);
            p1[i] = __expf(s1[i] - mn);
            ps[i] = p0[i] + p1[i];
            m_[i] = mn;
        }
#pragma unroll
        for (int d = 1; d < 16; d <<= 1) {
#pragma unroll
            for (int i = 0; i < 4; ++i) ps[i] += __shfl_xor(ps[i], d);
        }
#pragma unroll
        for (int i = 0; i < 4; ++i) l_[i] = l_[i] * scl[i] + ps[i];
#pragma unroll
        for (int dg = 0; dg < 4; ++dg)
#pragma unroll
            for (int i = 0; i < 4; ++i) oacc[dg][i] *= scl[i];
#pragma unroll
        for (int i = 0; i < 4; ++i) {
            Ps[w][lg * 4 + i][lr]      = f2bf(p0[i]);
            Ps[w][lg * 4 + i][16 + lr] = f2bf(p1[i]);
        }
        __syncthreads();
        s16x8 pa = *(const s16x8*)&Ps[w][lr][lg * 8];
#pragma unroll
        for (int dg = 0; dg < 4; ++dg) {
            s16x8 vf = *(const s16x8*)&Vt[dg * 16 + lr][lg * 8];
            oacc[dg] = __builtin_amdgcn_mfma_f32_16x16x32_bf16(pa, vf, oacc[dg], 0, 0, 0);
        }
        __syncthreads();
    }
    unsigned short* orow = o + ((size_t)(b * CAP_ + qbase)) * D_ + h * 64;
#pragma unroll
    for (int i = 0; i < 4; ++i) {
        float inv = 1.f / l_[i];
#pragma unroll
        for (int dg = 0; dg < 4; ++dg)
            orow[(size_t)i * D_ + dg * 16 + lr] = f2bf(oacc[dg][i] * inv);
    }
}

// ---------------- y = x_sel + xattn; h2 = rmsnorm(y, g2) ----------------
__global__ __launch_bounds__(256) void k_add_rms(const float* __restrict__ x,
                                                 const int* __restrict__ idx,
                                                 const unsigned short* __restrict__ xattn,
                                                 const float* __restrict__ g,
                                                 unsigned short* __restrict__ y,
                                                 unsigned short* __restrict__ h) {
    int r = blockIdx.x;
    int b = r >> 9;
    int src = idx[r] & (T_ - 1);
    int c = threadIdx.x * 4;
    const float* xr = x + ((size_t)b * T_ + src) * D_;
    float4 xv = *(const float4*)(xr + c);
    size_t off = (size_t)r * D_ + c;
    ushort4 a4 = *(const ushort4*)(xattn + off);
    float v0 = xv.x + bf2f(a4.x);
    float v1 = xv.y + bf2f(a4.y);
    float v2 = xv.z + bf2f(a4.z);
    float v3 = xv.w + bf2f(a4.w);
    float ss = v0*v0 + v1*v1 + v2*v2 + v3*v3;
#pragma unroll
    for (int o = 32; o; o >>= 1) ss += __shfl_xor(ss, o);
    __shared__ float red[4];
    int lane = threadIdx.x & 63, w = threadIdx.x >> 6;
    if (lane == 0) red[w] = ss;
    __syncthreads();
    float tot = red[0] + red[1] + red[2] + red[3];
    float scale = rsqrtf(tot * (1.f / D_) + 1e-6f);
    ushort4 yv;
    yv.x = f2bf(v0); yv.y = f2bf(v1); yv.z = f2bf(v2); yv.w = f2bf(v3);
    *(ushort4*)(y + off) = yv;
    float4 gv = *(const float4*)(g + c);
    ushort4 hv;
    hv.x = f2bf(v0 * scale * gv.x);
    hv.y = f2bf(v1 * scale * gv.y);
    hv.z = f2bf(v2 * scale * gv.z);
    hv.w = f2bf(v3 * scale * gv.w);
    *(ushort4*)(h + off) = hv;
}

// ---------------- scatter: out[b, idx, :] = y + xff  (fp32 out) ----------------
__global__ __launch_bounds__(256) void k_scatter(const unsigned short* __restrict__ y,
                                                 const unsigned short* __restrict__ xff,
                                                 const int* __restrict__ idx,
                                                 float* __restrict__ out) {
    int r = blockIdx.x;
    int b = r >> 9;
    int dst = idx[r] & (T_ - 1);
    int c = threadIdx.x * 4;
    size_t src = (size_t)r * D_ + c;
    ushort4 a4 = *(const ushort4*)(y + src);
    ushort4 f4 = *(const ushort4*)(xff + src);
    float4 o4;
    o4.x = bf2f(a4.x) + bf2f(f4.x);
    o4.y = bf2f(a4.y) + bf2f(f4.y);
    o4.z = bf2f(a4.z) + bf2f(f4.z);
    o4.w = bf2f(a4.w) + bf2f(f4.w);
    *(float4*)(out + ((size_t)b * T_ + dst) * D_ + c) = o4;
}

extern "C" void kernel_launch(void* const* d_in, const int* in_sizes, int n_in,
                              void* d_out, int out_size, void* d_ws, size_t ws_size,
                              hipStream_t stream) {
    const float* x     = (const float*)d_in[0];
    const float* w_rt  = (const float*)d_in[1];
    const float* W_qkv = (const float*)d_in[2];
    const float* W_out = (const float*)d_in[3];
    const float* g1    = (const float*)d_in[4];
    const float* g2    = (const float*)d_in[5];
    const float* W1    = (const float*)d_in[6];
    const float* W2    = (const float*)d_in[7];
    const float* W3    = (const float*)d_in[8];
    float* out = (float*)d_out;

    // ---- workspace: ~37 MiB (identical to r15/r16) ----
    char* p = (char*)d_ws;
    float* scores = (float*)p;
    int*   idx    = (int*)(p + 65536);
    size_t off = 131072;
    const size_t WPAD = (size_t)DFFR * D_;
    unsigned short* WBIG = (unsigned short*)(p + off); off += 2 * WPAD * 2;
    unsigned short* WB2  = WBIG + WPAD;
    unsigned short* R1   = (unsigned short*)(p + off); off += (size_t)M_*3*D_*2;
    unsigned short* R2   = (unsigned short*)(p + off); off += (size_t)M_*D_*2;
    unsigned short* R3   = (unsigned short*)(p + off); off += (size_t)M_*D_*2;
    unsigned short* R4   = (unsigned short*)(p + off); off += (size_t)M_*D_*2;

    unsigned short* h1    = R2;
    unsigned short* qkvb  = R1;
    unsigned short* attno = R2;   // after h1 dead
    unsigned short* xattn = R3;
    unsigned short* ybuf  = R4;
    unsigned short* h2b   = R2;   // after attno dead
    unsigned short* fbuf  = R1;   // after qkvb dead; [2048][DFFP]
    unsigned short* xffb  = R3;   // after xattn dead

    // 1. out = x
    k_copyf<<<2048, 256, 0, stream>>>((const float4*)x, (float4*)out, (B_*T_*D_) / 4);
    // 2. router scores
    k_router<<<(B_*T_) / 4, 256, 0, stream>>>(x, w_rt, scores);
    // 3. exact top-k (radix select, wave-parallel scan)
    k_topk<<<B_, 1024, 0, stream>>>(scores, idx);
    // 4. gather + rmsnorm(g1) -> h1 (bf16)
    k_gather_rms<<<M_, 256, 0, stream>>>(x, idx, g1, h1);
    // 5. qkv = h1 @ W_qkv^T   [2048 x 3072], K=1024
    k_f2b<<<2048, 256, 0, stream>>>((const float4*)W_qkv, (ushort4*)WBIG, (3*D_*D_) / 4);
    k_gemm64g<<<dim3(M_/64, 3*D_/128), 256, 0, stream>>>(h1, WBIG, qkvb, 3*D_, D_);
    // 6. MFMA flash attention
    k_attn_mfma<<<dim3(CAP_/64, H_, B_), 256, 0, stream>>>(qkvb, attno);
    // 7. x_attn = o @ W_out^T  [2048 x 1024], K=1024
    k_f2b<<<1024, 256, 0, stream>>>((const float4*)W_out, (ushort4*)WBIG, (D_*D_) / 4);
    k_gemm64g<<<dim3(M_/64, D_/128), 256, 0, stream>>>(attno, WBIG, xattn, D_, D_);
    // 8. y = x_sel + xattn; h2 = rmsnorm(y, g2)
    k_add_rms<<<M_, 256, 0, stream>>>(x, idx, xattn, g2, ybuf, h2b);
    // 9+10. f = silu(h2@W1^T) * (h2@W2^T)  — FUSED
    k_f2b_rowpad<<<2048, 256, 0, stream>>>(W1, WBIG, D_/8, DFF_, DFFR*(D_/8));
    k_f2b_rowpad<<<2048, 256, 0, stream>>>(W2, WB2,  D_/8, DFF_, DFFR*(D_/8));
    k_gemm64g2<<<dim3(M_/64, DFFR/128), 256, 0, stream>>>(h2b, WBIG, WB2, fbuf,
                                                          DFFP, D_);
    // 11. x_ff = f @ W3^T   [2048 x 1024], K=DFFP
    k_f2b_pad<<<2048, 256, 0, stream>>>(W3, WBIG, DFF_, DFFP, D_);
    k_gemm64g<<<dim3(M_/64, D_/128), 256, 0, stream>>>(fbuf, WBIG, xffb, D_, DFFP);
    // 12. out[b, idx, :] = y + x_ff  (fp32)
    k_scatter<<<M_, 256, 0, stream>>>(ybuf, xffb, idx, out);
}

// Round 18
// 216.350 us; speedup vs baseline: 1.6429x; 1.0291x over previous
//
#include <hip/hip_runtime.h>
#include <hip/hip_bf16.h>

// MoD transformer block: B=4, T=4096, D=1024, H=16, HD=64, CAP=512, DFF=2730
// Inputs fp32, output fp32. Round 18:
//  (a) GEMMs double-buffered (2-phase): issue next-tile global_load_lds before
//      computing current tile; one barrier per K-step. r17 GEMMs exposed full
//      HBM latency between stage and barrier (MfmaUtil 10%, occ 9.8%).
//  (b) copyf fused into router (one x read serves pass-through + scores).

#define B_   4
#define T_   4096
#define D_   1024
#define H_   16
#define HD_  64
#define CAP_ 512
#define DFF_ 2730
#define DFFP 2752               // DFF padded to mult of 64 (K-path)
#define DFFR 2816               // DFF padded to mult of 128 (B-row tiles)
#define M_   (B_*CAP_)          // 2048 selected rows total

typedef __attribute__((ext_vector_type(8))) short          s16x8;
typedef __attribute__((ext_vector_type(8))) unsigned short u16x8;
typedef __attribute__((ext_vector_type(4))) float          f32x4;

__device__ __forceinline__ float bf2f(unsigned short u) {
    union { float f; unsigned int i; } v; v.i = ((unsigned int)u) << 16; return v.f;
}
__device__ __forceinline__ unsigned short f2bf(float f) {
    union { float f; unsigned int i; } v; v.f = f;
    unsigned int r = v.i + 0x7fffu + ((v.i >> 16) & 1u);   // RNE
    return (unsigned short)(r >> 16);
}

// async global->LDS, 16B per lane; LDS dest = wave-uniform base + lane*16
__device__ __forceinline__ void gload_lds16(const unsigned short* g, unsigned short* l) {
    __builtin_amdgcn_global_load_lds(
        (const __attribute__((address_space(1))) unsigned int*)g,
        (__attribute__((address_space(3))) unsigned int*)l, 16, 0, 0);
}

// ---------------- fused: out = x (fp32) + router scores ----------------
// one wave per token row: read row once, write pass-through, dot with wr.
__global__ __launch_bounds__(256) void k_copy_router(const float* __restrict__ x,
                                                     const float* __restrict__ wr,
                                                     float* __restrict__ out,
                                                     float* __restrict__ sc) {
    int gw   = (blockIdx.x * 256 + threadIdx.x) >> 6;   // 0..B*T-1
    int lane = threadIdx.x & 63;
    const float* row = x + (size_t)gw * D_;
    float* orow = out + (size_t)gw * D_;
    float s = 0.f;
#pragma unroll
    for (int p = 0; p < 4; ++p) {
        int c = p * 256 + lane * 4;
        float4 xv = *(const float4*)(row + c);
        float4 wv = *(const float4*)(wr + c);
        *(float4*)(orow + c) = xv;
        s += xv.x * wv.x + xv.y * wv.y + xv.z * wv.z + xv.w * wv.w;
    }
#pragma unroll
    for (int o = 32; o; o >>= 1) s += __shfl_xor(s, o);
    if (lane == 0) sc[gw] = s;
}

// ---------------- fp32 -> bf16 flat convert ----------------
__global__ __launch_bounds__(256) void k_f2b(const float4* __restrict__ s,
                                             ushort4* __restrict__ d, int n4) {
    int i = blockIdx.x * 256 + threadIdx.x;
    int st = gridDim.x * 256;
    for (; i < n4; i += st) {
        float4 v = s[i];
        ushort4 o;
        o.x = f2bf(v.x); o.y = f2bf(v.y); o.z = f2bf(v.z); o.w = f2bf(v.w);
        d[i] = o;
    }
}

// ---------------- fp32 [rows][K] -> bf16 [rowsP][K], pad ROWS zeroed ----------------
__global__ __launch_bounds__(256) void k_f2b_rowpad(const float* __restrict__ src,
                                                    unsigned short* __restrict__ dst,
                                                    int kc, int rows, int total) {
    int g = blockIdx.x * 256 + threadIdx.x;
    int st = gridDim.x * 256;
    for (; g < total; g += st) {
        int row = g / kc;
        u16x8 v = {0, 0, 0, 0, 0, 0, 0, 0};
        if (row < rows) {
            const float* s = src + ((size_t)g) * 8;
#pragma unroll
            for (int j = 0; j < 2; ++j) {
                float4 f = *(const float4*)(s + 4 * j);
                v[4*j]   = f2bf(f.x); v[4*j+1] = f2bf(f.y);
                v[4*j+2] = f2bf(f.z); v[4*j+3] = f2bf(f.w);
            }
        }
        *(u16x8*)(dst + (size_t)g * 8) = v;
    }
}

// ---------------- fp32 [rows][K] -> bf16 [rows][Kp], pad COLS zeroed ----------------
__global__ __launch_bounds__(256) void k_f2b_pad(const float* __restrict__ src,
                                                 unsigned short* __restrict__ dst,
                                                 int K, int Kp, int rows) {
    int g = blockIdx.x * 256 + threadIdx.x;
    int ng = rows * (Kp >> 3);
    int st = gridDim.x * 256;
    for (; g < ng; g += st) {
        int row = g / (Kp >> 3);
        int c = (g - row * (Kp >> 3)) << 3;
        const float* s = src + (size_t)row * K + c;
        u16x8 v;
        if (c + 8 <= K) {
#pragma unroll
            for (int j = 0; j < 4; ++j) {
                float2 f = *(const float2*)(s + 2 * j);
                v[2*j] = f2bf(f.x); v[2*j+1] = f2bf(f.y);
            }
        } else {
#pragma unroll
            for (int j = 0; j < 8; ++j) v[j] = (c + j < K) ? f2bf(s[j]) : (unsigned short)0;
        }
        *(u16x8*)(dst + (size_t)row * Kp + c) = v;
    }
}

// ---------------- exact top-k via radix select + rank scatter ----------------
__global__ __launch_bounds__(1024) void k_topk(const float* __restrict__ sc,
                                               int* __restrict__ idx) {
    __shared__ unsigned int hist[256];
    __shared__ unsigned long long okeys[CAP_];
    __shared__ unsigned int ecand[T_];
    __shared__ unsigned int sprefix;
    __shared__ int skneed;
    __shared__ unsigned int scnt, ecnt;
    int t = threadIdx.x;
    const float* s = sc + (size_t)blockIdx.x * T_;

    unsigned int sb[4], ei[4];
#pragma unroll
    for (int j = 0; j < 4; ++j) {
        int i = j * 1024 + t;
        union { float f; unsigned int u; } v; v.f = s[i];
        unsigned int k = (v.u & 0x80000000u) ? ~v.u : (v.u | 0x80000000u);
        sb[j] = ~k;
        ei[j] = (unsigned int)i;
    }
    if (t == 0) { sprefix = 0; skneed = CAP_; scnt = 0; ecnt = 0; }

#pragma unroll
    for (int rs = 24; rs >= 0; rs -= 8) {
        if (t < 256) hist[t] = 0;
        __syncthreads();
        unsigned int pfx = sprefix;
#pragma unroll
        for (int j = 0; j < 4; ++j) {
            if (((unsigned long long)(sb[j] ^ pfx) >> (rs + 8)) == 0ULL)
                atomicAdd(&hist[(sb[j] >> rs) & 255u], 1u);
        }
        __syncthreads();
        if (t < 64) {
            unsigned int h0 = hist[t * 4], h1 = hist[t * 4 + 1];
            unsigned int h2 = hist[t * 4 + 2], h3 = hist[t * 4 + 3];
            unsigned int lsum = h0 + h1 + h2 + h3;
            unsigned int run = lsum;
#pragma unroll
            for (int d = 1; d < 64; d <<= 1) {
                unsigned int v = __shfl_up(run, d);
                if (t >= d) run += v;
            }
            unsigned int excl = run - lsum;
            int need = skneed;
            if (excl < (unsigned int)need && run >= (unsigned int)need) {
                unsigned int cum = excl;
                int b = t * 4;
                if (cum + h0 < (unsigned int)need) { cum += h0; ++b;
                    if (cum + h1 < (unsigned int)need) { cum += h1; ++b;
                        if (cum + h2 < (unsigned int)need) { cum += h2; ++b; } } }
                sprefix = pfx | ((unsigned int)b << rs);
                skneed = need - (int)cum;
            }
        }
        __syncthreads();
    }

    unsigned int Sstar = sprefix;
    int neq = skneed;
#pragma unroll
    for (int j = 0; j < 4; ++j) {
        if (sb[j] < Sstar) {
            unsigned int p = atomicAdd(&scnt, 1u);
            okeys[p] = ((unsigned long long)sb[j] << 32) | ei[j];
        } else if (sb[j] == Sstar) {
            unsigned int p = atomicAdd(&ecnt, 1u);
            ecand[p] = ei[j];
        }
    }
    __syncthreads();
    if (t == 0) {
        unsigned int base = scnt;
        unsigned int ne = ecnt;
        for (int q = 0; q < neq; ++q) {
            unsigned int mn = 0xffffffffu; int mi = 0;
            for (unsigned int e = 0; e < ne; ++e)
                if (ecand[e] < mn) { mn = ecand[e]; mi = (int)e; }
            okeys[base + q] = ((unsigned long long)Sstar << 32) | mn;
            ecand[mi] = 0xffffffffu;
        }
    }
    __syncthreads();
    if (t < CAP_) {
        unsigned long long mine = okeys[t];
        int r = 0;
#pragma unroll 8
        for (int q = 0; q < CAP_; ++q) r += (okeys[q] < mine) ? 1 : 0;
        idx[blockIdx.x * CAP_ + r] = (int)(mine & 0xffffffffu);
    }
}

// ---------------- gather + RMSNorm(g1) -> h (bf16) ----------------
__global__ __launch_bounds__(256) void k_gather_rms(const float* __restrict__ x,
                                                    const int* __restrict__ idx,
                                                    const float* __restrict__ g,
                                                    unsigned short* __restrict__ h) {
    int r = blockIdx.x;
    int b = r >> 9;
    int src = idx[r] & (T_ - 1);
    const float* xr = x + ((size_t)b * T_ + src) * D_;
    int c = threadIdx.x * 4;
    float4 xv = *(const float4*)(xr + c);
    float ss = xv.x*xv.x + xv.y*xv.y + xv.z*xv.z + xv.w*xv.w;
#pragma unroll
    for (int o = 32; o; o >>= 1) ss += __shfl_xor(ss, o);
    __shared__ float red[4];
    int lane = threadIdx.x & 63, w = threadIdx.x >> 6;
    if (lane == 0) red[w] = ss;
    __syncthreads();
    float tot = red[0] + red[1] + red[2] + red[3];
    float scale = rsqrtf(tot * (1.f / D_) + 1e-6f);
    float4 gv = *(const float4*)(g + c);
    ushort4 hv;
    hv.x = f2bf(xv.x * scale * gv.x);
    hv.y = f2bf(xv.y * scale * gv.y);
    hv.z = f2bf(xv.z * scale * gv.z);
    hv.w = f2bf(xv.w * scale * gv.w);
    *(ushort4*)(h + (size_t)r * D_ + c) = hv;
}

// ---------------- MFMA GEMM 64x128 (BK=64), DOUBLE-BUFFERED 2-phase ----------------
// prologue: stage buf0; loop: issue stage(buf^1, next) -> ds_read+MFMA(buf)
// -> barrier (drains vmcnt for next tile). One barrier per K-step.
__global__ __launch_bounds__(256) void k_gemm64g(const unsigned short* __restrict__ A,
                                                 const unsigned short* __restrict__ Bw,
                                                 unsigned short* __restrict__ C,
                                                 int Nout, int Kr) {
    __shared__ __align__(16) unsigned short As[2][64 * 64];    // 16KB
    __shared__ __align__(16) unsigned short Bs[2][128 * 64];   // 32KB
    int m0 = blockIdx.x * 64;
    int n0 = blockIdx.y * 128;
    int t = threadIdx.x;
    int w = t >> 6, lane = t & 63;
    int lr = lane & 15, lg = lane >> 4;
    int l8 = lane >> 3, lm8 = lane & 7;

    int arow = w * 16 + l8;           // + j*8
    int acb0 = lm8 ^ (arow & 7), acb1 = lm8 ^ ((arow + 8) & 7);
    int brow = w * 32 + l8;
    int bcb[4];
#pragma unroll
    for (int j = 0; j < 4; ++j) bcb[j] = lm8 ^ ((brow + j * 8) & 7);

    f32x4 acc[4][2];
#pragma unroll
    for (int mi = 0; mi < 4; ++mi)
#pragma unroll
        for (int ni = 0; ni < 2; ++ni) acc[mi][ni] = {0.f, 0.f, 0.f, 0.f};

#define STAGE_G(buf, k0)                                                          \
    {                                                                             \
        gload_lds16(A + (size_t)(m0 + arow) * Kr + (k0) + acb0 * 8,               \
                    &As[buf][(w * 16) * 64]);                                     \
        gload_lds16(A + (size_t)(m0 + arow + 8) * Kr + (k0) + acb1 * 8,           \
                    &As[buf][(w * 16 + 8) * 64]);                                 \
        _Pragma("unroll")                                                         \
        for (int j = 0; j < 4; ++j)                                               \
            gload_lds16(Bw + (size_t)(n0 + brow + j * 8) * Kr + (k0) + bcb[j] * 8,\
                        &Bs[buf][(w * 32 + j * 8) * 64]);                         \
    }

    int nk = Kr >> 6;
    STAGE_G(0, 0);
    __syncthreads();
    for (int kt = 0; kt < nk; ++kt) {
        int cur = kt & 1;
        if (kt + 1 < nk) STAGE_G(cur ^ 1, (kt + 1) << 6);
#pragma unroll
        for (int kh = 0; kh < 2; ++kh) {
            s16x8 af[4], bf[2];
#pragma unroll
            for (int i = 0; i < 4; ++i) {
                int row = i * 16 + lr;
                int pb = (kh * 4 + lg) ^ (row & 7);
                af[i] = *(const s16x8*)&As[cur][row * 64 + pb * 8];
            }
#pragma unroll
            for (int i = 0; i < 2; ++i) {
                int row = w * 32 + i * 16 + lr;
                int pb = (kh * 4 + lg) ^ (row & 7);
                bf[i] = *(const s16x8*)&Bs[cur][row * 64 + pb * 8];
            }
#pragma unroll
            for (int mi = 0; mi < 4; ++mi)
#pragma unroll
                for (int ni = 0; ni < 2; ++ni)
                    acc[mi][ni] = __builtin_amdgcn_mfma_f32_16x16x32_bf16(af[mi], bf[ni],
                                                                          acc[mi][ni], 0, 0, 0);
        }
        __syncthreads();
    }
#undef STAGE_G
    int orow0 = m0 + (lg << 2);
    int ocol0 = n0 + w * 32 + lr;
#pragma unroll
    for (int ni = 0; ni < 2; ++ni) {
        int col = ocol0 + ni * 16;
        if (col < Nout) {
#pragma unroll
            for (int mi = 0; mi < 4; ++mi)
#pragma unroll
                for (int i = 0; i < 4; ++i)
                    C[(size_t)(orow0 + mi * 16 + i) * Nout + col] = f2bf(acc[mi][ni][i]);
        }
    }
}

// ---------------- FUSED W1/W2 GEMM, DOUBLE-BUFFERED: F = silu(A*B1^T)*(A*B2^T) ----------------
__global__ __launch_bounds__(256) void k_gemm64g2(const unsigned short* __restrict__ A,
                                                  const unsigned short* __restrict__ B1,
                                                  const unsigned short* __restrict__ B2,
                                                  unsigned short* __restrict__ F,
                                                  int Nout, int Kr) {
    __shared__ __align__(16) unsigned short As[2][64 * 64];     // 16KB
    __shared__ __align__(16) unsigned short B1s[2][128 * 64];   // 32KB
    __shared__ __align__(16) unsigned short B2s[2][128 * 64];   // 32KB
    int m0 = blockIdx.x * 64;
    int n0 = blockIdx.y * 128;
    int t = threadIdx.x;
    int w = t >> 6, lane = t & 63;
    int lr = lane & 15, lg = lane >> 4;
    int l8 = lane >> 3, lm8 = lane & 7;

    int arow = w * 16 + l8;
    int acb0 = lm8 ^ (arow & 7), acb1 = lm8 ^ ((arow + 8) & 7);
    int brow = w * 32 + l8;
    int bcb[4];
#pragma unroll
    for (int j = 0; j < 4; ++j) bcb[j] = lm8 ^ ((brow + j * 8) & 7);

    f32x4 accU[4][2], accG[4][2];
#pragma unroll
    for (int mi = 0; mi < 4; ++mi)
#pragma unroll
        for (int ni = 0; ni < 2; ++ni) {
            accU[mi][ni] = {0.f, 0.f, 0.f, 0.f};
            accG[mi][ni] = {0.f, 0.f, 0.f, 0.f};
        }

#define STAGE_G2(buf, k0)                                                          \
    {                                                                              \
        gload_lds16(A + (size_t)(m0 + arow) * Kr + (k0) + acb0 * 8,                \
                    &As[buf][(w * 16) * 64]);                                      \
        gload_lds16(A + (size_t)(m0 + arow + 8) * Kr + (k0) + acb1 * 8,            \
                    &As[buf][(w * 16 + 8) * 64]);                                  \
        _Pragma("unroll")                                                          \
        for (int j = 0; j < 4; ++j) {                                              \
            size_t goff = (size_t)(n0 + brow + j * 8) * Kr + (k0) + bcb[j] * 8;    \
            gload_lds16(B1 + goff, &B1s[buf][(w * 32 + j * 8) * 64]);              \
            gload_lds16(B2 + goff, &B2s[buf][(w * 32 + j * 8) * 64]);              \
        }                                                                          \
    }

    int nk = Kr >> 6;
    STAGE_G2(0, 0);
    __syncthreads();
    for (int kt = 0; kt < nk; ++kt) {
        int cur = kt & 1;
        if (kt + 1 < nk) STAGE_G2(cur ^ 1, (kt + 1) << 6);
#pragma unroll
        for (int kh = 0; kh < 2; ++kh) {
            s16x8 af[4], b1f[2], b2f[2];
#pragma unroll
            for (int i = 0; i < 4; ++i) {
                int row = i * 16 + lr;
                int pb = (kh * 4 + lg) ^ (row & 7);
                af[i] = *(const s16x8*)&As[cur][row * 64 + pb * 8];
            }
#pragma unroll
            for (int i = 0; i < 2; ++i) {
                int row = w * 32 + i * 16 + lr;
                int pb = (kh * 4 + lg) ^ (row & 7);
                b1f[i] = *(const s16x8*)&B1s[cur][row * 64 + pb * 8];
                b2f[i] = *(const s16x8*)&B2s[cur][row * 64 + pb * 8];
            }
#pragma unroll
            for (int mi = 0; mi < 4; ++mi)
#pragma unroll
                for (int ni = 0; ni < 2; ++ni) {
                    accU[mi][ni] = __builtin_amdgcn_mfma_f32_16x16x32_bf16(af[mi], b1f[ni],
                                                                           accU[mi][ni], 0, 0, 0);
                    accG[mi][ni] = __builtin_amdgcn_mfma_f32_16x16x32_bf16(af[mi], b2f[ni],
                                                                           accG[mi][ni], 0, 0, 0);
                }
        }
        __syncthreads();
    }
#undef STAGE_G2
    int orow0 = m0 + (lg << 2);
    int ocol0 = n0 + w * 32 + lr;
#pragma unroll
    for (int ni = 0; ni < 2; ++ni) {
        int col = ocol0 + ni * 16;
        if (col < Nout) {
#pragma unroll
            for (int mi = 0; mi < 4; ++mi)
#pragma unroll
                for (int i = 0; i < 4; ++i) {
                    float u = accU[mi][ni][i];
                    float sl = u / (1.f + __expf(-u));
                    F[(size_t)(orow0 + mi * 16 + i) * Nout + col] = f2bf(sl * accG[mi][ni][i]);
                }
        }
    }
}

// ---------------- MFMA flash attention (causal, gathered order) ----------------
__global__ __launch_bounds__(256) void k_attn_mfma(const unsigned short* __restrict__ qkv,
                                                   unsigned short* __restrict__ o) {
    __shared__ __align__(16) unsigned short Ks[32][72];
    __shared__ __align__(16) unsigned short Vt[64][40];
    __shared__ __align__(16) unsigned short Ps[4][16][40];
    int qt = blockIdx.x, h = blockIdx.y, b = blockIdx.z;
    int q0 = qt * 64;
    int t = threadIdx.x, w = t >> 6, lane = t & 63;
    int lr = lane & 15, lg = lane >> 4;
    const unsigned short* base = qkv + (size_t)b * CAP_ * 3 * D_;

    int qrow = q0 + w * 16 + lr;
    const unsigned short* qp = base + (size_t)qrow * 3 * D_ + h * 64;
    s16x8 aq0 = *(const s16x8*)(qp + lg * 8);
    s16x8 aq1 = *(const s16x8*)(qp + 32 + lg * 8);

    f32x4 zero = {0.f, 0.f, 0.f, 0.f};
    f32x4 oacc[4] = {zero, zero, zero, zero};
    float m_[4], l_[4];
#pragma unroll
    for (int i = 0; i < 4; ++i) { m_[i] = -3.0e38f; l_[i] = 0.f; }

    int qbase = q0 + w * 16 + lg * 4;
    int ntile = (q0 + 64) >> 5;

    int skv = t >> 3, sc = (t & 7) * 8;
    for (int kt = 0; kt < ntile; ++kt) {
        int kv0 = kt << 5;
        {
            const unsigned short* kr = base + (size_t)(kv0 + skv) * 3 * D_ + D_     + h * 64 + sc;
            const unsigned short* vr = base + (size_t)(kv0 + skv) * 3 * D_ + 2 * D_ + h * 64 + sc;
            *(u16x8*)&Ks[skv][sc] = *(const u16x8*)kr;
            u16x8 vv = *(const u16x8*)vr;
#pragma unroll
            for (int j = 0; j < 8; ++j) Vt[sc + j][skv] = vv[j];
        }
        __syncthreads();
        f32x4 s0 = zero, s1 = zero;
        s16x8 k00 = *(const s16x8*)&Ks[lr][lg * 8];
        s16x8 k01 = *(const s16x8*)&Ks[lr][32 + lg * 8];
        s16x8 k10 = *(const s16x8*)&Ks[16 + lr][lg * 8];
        s16x8 k11 = *(const s16x8*)&Ks[16 + lr][32 + lg * 8];
        s0 = __builtin_amdgcn_mfma_f32_16x16x32_bf16(aq0, k00, s0, 0, 0, 0);
        s0 = __builtin_amdgcn_mfma_f32_16x16x32_bf16(aq1, k01, s0, 0, 0, 0);
        s1 = __builtin_amdgcn_mfma_f32_16x16x32_bf16(aq0, k10, s1, 0, 0, 0);
        s1 = __builtin_amdgcn_mfma_f32_16x16x32_bf16(aq1, k11, s1, 0, 0, 0);
#pragma unroll
        for (int i = 0; i < 4; ++i) {
            float v0 = s0[i] * 0.125f, v1 = s1[i] * 0.125f;
            if (kv0 + lr      > qbase + i) v0 = -3.0e38f;
            if (kv0 + 16 + lr > qbase + i) v1 = -3.0e38f;
            s0[i] = v0; s1[i] = v1;
        }
        float pm[4];
#pragma unroll
        for (int i = 0; i < 4; ++i) pm[i] = fmaxf(s0[i], s1[i]);
#pragma unroll
        for (int d = 1; d < 16; d <<= 1) {
#pragma unroll
            for (int i = 0; i < 4; ++i) pm[i] = fmaxf(pm[i], __shfl_xor(pm[i], d));
        }
        float p0[4], p1[4], ps[4], scl[4];
#pragma unroll
        for (int i = 0; i < 4; ++i) {
            float mn = fmaxf(m_[i], pm[i]);
            scl[i] = __expf(m_[i] - mn);
            p0[i] = __expf(s0[i] - mn);
            p1[i] = __expf(s1[i] - mn);
            ps[i] = p0[i] + p1[i];
            m_[i] = mn;
        }
#pragma unroll
        for (int d = 1; d < 16; d <<= 1) {
#pragma unroll
            for (int i = 0; i < 4; ++i) ps[i] += __shfl_xor(ps[i], d);
        }
#pragma unroll
        for (int i = 0; i < 4; ++i) l_[i] = l_[i] * scl[i] + ps[i];
#pragma unroll
        for (int dg = 0; dg < 4; ++dg)
#pragma unroll
            for (int i = 0; i < 4; ++i) oacc[dg][i] *= scl[i];
#pragma unroll
        for (int i = 0; i < 4; ++i) {
            Ps[w][lg * 4 + i][lr]      = f2bf(p0[i]);
            Ps[w][lg * 4 + i][16 + lr] = f2bf(p1[i]);
        }
        __syncthreads();
        s16x8 pa = *(const s16x8*)&Ps[w][lr][lg * 8];
#pragma unroll
        for (int dg = 0; dg < 4; ++dg) {
            s16x8 vf = *(const s16x8*)&Vt[dg * 16 + lr][lg * 8];
            oacc[dg] = __builtin_amdgcn_mfma_f32_16x16x32_bf16(pa, vf, oacc[dg], 0, 0, 0);
        }
        __syncthreads();
    }
    unsigned short* orow = o + ((size_t)(b * CAP_ + qbase)) * D_ + h * 64;
#pragma unroll
    for (int i = 0; i < 4; ++i) {
        float inv = 1.f / l_[i];
#pragma unroll
        for (int dg = 0; dg < 4; ++dg)
            orow[(size_t)i * D_ + dg * 16 + lr] = f2bf(oacc[dg][i] * inv);
    }
}

// ---------------- y = x_sel + xattn; h2 = rmsnorm(y, g2) ----------------
__global__ __launch_bounds__(256) void k_add_rms(const float* __restrict__ x,
                                                 const int* __restrict__ idx,
                                                 const unsigned short* __restrict__ xattn,
                                                 const float* __restrict__ g,
                                                 unsigned short* __restrict__ y,
                                                 unsigned short* __restrict__ h) {
    int r = blockIdx.x;
    int b = r >> 9;
    int src = idx[r] & (T_ - 1);
    int c = threadIdx.x * 4;
    const float* xr = x + ((size_t)b * T_ + src) * D_;
    float4 xv = *(const float4*)(xr + c);
    size_t off = (size_t)r * D_ + c;
    ushort4 a4 = *(const ushort4*)(xattn + off);
    float v0 = xv.x + bf2f(a4.x);
    float v1 = xv.y + bf2f(a4.y);
    float v2 = xv.z + bf2f(a4.z);
    float v3 = xv.w + bf2f(a4.w);
    float ss = v0*v0 + v1*v1 + v2*v2 + v3*v3;
#pragma unroll
    for (int o = 32; o; o >>= 1) ss += __shfl_xor(ss, o);
    __shared__ float red[4];
    int lane = threadIdx.x & 63, w = threadIdx.x >> 6;
    if (lane == 0) red[w] = ss;
    __syncthreads();
    float tot = red[0] + red[1] + red[2] + red[3];
    float scale = rsqrtf(tot * (1.f / D_) + 1e-6f);
    ushort4 yv;
    yv.x = f2bf(v0); yv.y = f2bf(v1); yv.z = f2bf(v2); yv.w = f2bf(v3);
    *(ushort4*)(y + off) = yv;
    float4 gv = *(const float4*)(g + c);
    ushort4 hv;
    hv.x = f2bf(v0 * scale * gv.x);
    hv.y = f2bf(v1 * scale * gv.y);
    hv.z = f2bf(v2 * scale * gv.z);
    hv.w = f2bf(v3 * scale * gv.w);
    *(ushort4*)(h + off) = hv;
}

// ---------------- scatter: out[b, idx, :] = y + xff  (fp32 out) ----------------
__global__ __launch_bounds__(256) void k_scatter(const unsigned short* __restrict__ y,
                                                 const unsigned short* __restrict__ xff,
                                                 const int* __restrict__ idx,
                                                 float* __restrict__ out) {
    int r = blockIdx.x;
    int b = r >> 9;
    int dst = idx[r] & (T_ - 1);
    int c = threadIdx.x * 4;
    size_t src = (size_t)r * D_ + c;
    ushort4 a4 = *(const ushort4*)(y + src);
    ushort4 f4 = *(const ushort4*)(xff + src);
    float4 o4;
    o4.x = bf2f(a4.x) + bf2f(f4.x);
    o4.y = bf2f(a4.y) + bf2f(f4.y);
    o4.z = bf2f(a4.z) + bf2f(f4.z);
    o4.w = bf2f(a4.w) + bf2f(f4.w);
    *(float4*)(out + ((size_t)b * T_ + dst) * D_ + c) = o4;
}

extern "C" void kernel_launch(void* const* d_in, const int* in_sizes, int n_in,
                              void* d_out, int out_size, void* d_ws, size_t ws_size,
                              hipStream_t stream) {
    const float* x     = (const float*)d_in[0];
    const float* w_rt  = (const float*)d_in[1];
    const float* W_qkv = (const float*)d_in[2];
    const float* W_out = (const float*)d_in[3];
    const float* g1    = (const float*)d_in[4];
    const float* g2    = (const float*)d_in[5];
    const float* W1    = (const float*)d_in[6];
    const float* W2    = (const float*)d_in[7];
    const float* W3    = (const float*)d_in[8];
    float* out = (float*)d_out;

    // ---- workspace: ~37 MiB (identical to r15-r17) ----
    char* p = (char*)d_ws;
    float* scores = (float*)p;
    int*   idx    = (int*)(p + 65536);
    size_t off = 131072;
    const size_t WPAD = (size_t)DFFR * D_;
    unsigned short* WBIG = (unsigned short*)(p + off); off += 2 * WPAD * 2;
    unsigned short* WB2  = WBIG + WPAD;
    unsigned short* R1   = (unsigned short*)(p + off); off += (size_t)M_*3*D_*2;
    unsigned short* R2   = (unsigned short*)(p + off); off += (size_t)M_*D_*2;
    unsigned short* R3   = (unsigned short*)(p + off); off += (size_t)M_*D_*2;
    unsigned short* R4   = (unsigned short*)(p + off); off += (size_t)M_*D_*2;

    unsigned short* h1    = R2;
    unsigned short* qkvb  = R1;
    unsigned short* attno = R2;   // after h1 dead
    unsigned short* xattn = R3;
    unsigned short* ybuf  = R4;
    unsigned short* h2b   = R2;   // after attno dead
    unsigned short* fbuf  = R1;   // after qkvb dead; [2048][DFFP]
    unsigned short* xffb  = R3;   // after xattn dead

    // 1+2. out = x (pass-through) + router scores, one x read
    k_copy_router<<<(B_*T_) / 4, 256, 0, stream>>>(x, w_rt, out, scores);
    // 3. exact top-k
    k_topk<<<B_, 1024, 0, stream>>>(scores, idx);
    // 4. gather + rmsnorm(g1) -> h1 (bf16)
    k_gather_rms<<<M_, 256, 0, stream>>>(x, idx, g1, h1);
    // 5. qkv = h1 @ W_qkv^T   [2048 x 3072], K=1024
    k_f2b<<<2048, 256, 0, stream>>>((const float4*)W_qkv, (ushort4*)WBIG, (3*D_*D_) / 4);
    k_gemm64g<<<dim3(M_/64, 3*D_/128), 256, 0, stream>>>(h1, WBIG, qkvb, 3*D_, D_);
    // 6. MFMA flash attention
    k_attn_mfma<<<dim3(CAP_/64, H_, B_), 256, 0, stream>>>(qkvb, attno);
    // 7. x_attn = o @ W_out^T  [2048 x 1024], K=1024
    k_f2b<<<1024, 256, 0, stream>>>((const float4*)W_out, (ushort4*)WBIG, (D_*D_) / 4);
    k_gemm64g<<<dim3(M_/64, D_/128), 256, 0, stream>>>(attno, WBIG, xattn, D_, D_);
    // 8. y = x_sel + xattn; h2 = rmsnorm(y, g2)
    k_add_rms<<<M_, 256, 0, stream>>>(x, idx, xattn, g2, ybuf, h2b);
    // 9+10. f = silu(h2@W1^T) * (h2@W2^T)  — FUSED
    k_f2b_rowpad<<<2048, 256, 0, stream>>>(W1, WBIG, D_/8, DFF_, DFFR*(D_/8));
    k_f2b_rowpad<<<2048, 256, 0, stream>>>(W2, WB2,  D_/8, DFF_, DFFR*(D_/8));
    k_gemm64g2<<<dim3(M_/64, DFFR/128), 256, 0, stream>>>(h2b, WBIG, WB2, fbuf,
                                                          DFFP, D_);
    // 11. x_ff = f @ W3^T   [2048 x 1024], K=DFFP
    k_f2b_pad<<<2048, 256, 0, stream>>>(W3, WBIG, DFF_, DFFP, D_);
    k_gemm64g<<<dim3(M_/64, D_/128), 256, 0, stream>>>(fbuf, WBIG, xffb, D_, DFFP);
    // 12. out[b, idx, :] = y + x_ff  (fp32)
    k_scatter<<<M_, 256, 0, stream>>>(ybuf, xffb, idx, out);
}